// Round 6
// baseline (543.478 us; speedup 1.0000x reference)
//
#include <hip/hip_runtime.h>
#include <hip/hip_bf16.h>
#include <math.h>

// ---------------------------------------------------------------------------
// Swin/SAM-style block. R14: 8-phase 256^2 GEMM (m198/m201 schedule) for
// qkv+fc1. Diagnosis: MfmaUtil pinned 16-18% across ALL tile/pipeline/occ
// permutations (R8-R13) = the 2-phase K-loop class's structural ~72%
// stage+vmcnt+barrier overhead (guide m233), not a BW wall. Fix is the
// 8-phase counted-vmcnt schedule: BK=64, 2 khalf planes, per phase
// {8 ds_read ; stage 1 half-tile ; [vmcnt(4) at odd phases] ; barrier ;
// 16 MFMA with setprio ; barrier}. Loads get 3-4 phases to land; newest
// tile never drained. proj/fc2 keep the R10 128-class kernel (best total).
// ---------------------------------------------------------------------------

#define DIMC 768
#define HEADS 12
#define WIN 14
#define NTOK 196
#define NWIN 50
#define MROWS 9800
#define YROWS 8192
#define MLP_HID 3072

using bf16x8 = __attribute__((ext_vector_type(8))) short;
using f32x4  = __attribute__((ext_vector_type(4))) float;

__device__ __forceinline__ float bf2f(unsigned short u) {
    return __uint_as_float(((unsigned)u) << 16);
}
__device__ __forceinline__ unsigned short f2bf(float f) {
    unsigned u = __float_as_uint(f);
    unsigned r = (u + 0x7fffu + ((u >> 16) & 1u)) >> 16;   // round-nearest-even
    return (unsigned short)r;
}
__device__ __forceinline__ void gl2lds16(const unsigned short* g, unsigned short* l) {
    __builtin_amdgcn_global_load_lds(
        (const __attribute__((address_space(1))) void*)g,
        (__attribute__((address_space(3))) void*)l, 16, 0, 0);
}

// Branchless exact-enough gelu: 0.5*v*(1+erf(v/sqrt(2))).
// erf via Abramowitz-Stegun 7.1.26 (max err 1.5e-7 < bf16 quantum).
__device__ __forceinline__ float fast_gelu(float v) {
    float u = v * 0.70710678118654752f;
    float a = fabsf(u);
    float t = __builtin_amdgcn_rcpf(fmaf(0.3275911f, a, 1.0f));
    float p = t * fmaf(t, fmaf(t, fmaf(t, fmaf(t, 1.061405429f, -1.453152027f),
                       1.421413741f), -0.284496736f), 0.254829592f);
    float e = __expf(-u * u);
    float er = fmaf(-p, e, 1.0f);            // erf(|u|)
    er = copysignf(er, v);
    return 0.5f * v * (1.0f + er);
}

// ---------------- fused 4-way weight transpose: W (K x N, f32) -> Wt (N x K, bf16)
// block ranges: [0,432) qkv  [432,576) proj  [576,1152) fc1  [1152,1728) fc2
__global__ __launch_bounds__(256) void transpose_all(
        const float* __restrict__ Wq, unsigned short* __restrict__ Tq,
        const float* __restrict__ Wp, unsigned short* __restrict__ Tp,
        const float* __restrict__ W1, unsigned short* __restrict__ T1,
        const float* __restrict__ W2, unsigned short* __restrict__ T2) {
    int id = blockIdx.x;
    const float* W; unsigned short* Wt; int K, N, nbx, rel;
    if (id < 432)       { W = Wq; Wt = Tq; K = 768;  N = 2304; nbx = 36; rel = id; }
    else if (id < 576)  { W = Wp; Wt = Tp; K = 768;  N = 768;  nbx = 12; rel = id - 432; }
    else if (id < 1152) { W = W1; Wt = T1; K = 768;  N = 3072; nbx = 48; rel = id - 576; }
    else                { W = W2; Wt = T2; K = 3072; N = 768;  nbx = 12; rel = id - 1152; }
    int bx = rel % nbx, by = rel / nbx;
    __shared__ float t[64][65];
    int k0 = by << 6, n0 = bx << 6;
    int tn = threadIdx.x & 63;
    int tk = threadIdx.x >> 6;
    #pragma unroll
    for (int r = 0; r < 16; r++) {
        int k = tk + r * 4;
        t[k][tn] = W[(size_t)(k0 + k) * N + n0 + tn];
    }
    __syncthreads();
    #pragma unroll
    for (int r = 0; r < 16; r++) {
        int n = tk + r * 4;
        Wt[(size_t)(n0 + n) * K + k0 + tn] = f2bf(t[tn][n]);
    }
}

// ---------------- LN1 + window partition (zeros in padding) ----------------
__global__ __launch_bounds__(256) void ln1_win_kernel(
        const float* __restrict__ x, const float* __restrict__ g,
        const float* __restrict__ b, unsigned short* __restrict__ h1) {
    int tid = threadIdx.x;
    int row = blockIdx.x * 4 + (tid >> 6);
    int lane = tid & 63;
    if (row >= MROWS) return;
    int w = row / NTOK, t = row % NTOK;
    int bi = w / 25, wr = w % 25;
    int gy = (wr / 5) * WIN + t / WIN;
    int gx = (wr % 5) * WIN + t % WIN;
    unsigned short* out = h1 + (size_t)row * DIMC;
    if (gy >= 64 || gx >= 64) {           // reference pads AFTER LN -> zeros
        #pragma unroll
        for (int j = 0; j < 12; j++) out[lane + 64 * j] = 0;
        return;
    }
    const float* xr = x + ((size_t)((bi * 64 + gy) * 64 + gx)) * DIMC;
    float v[12], s = 0.f;
    #pragma unroll
    for (int j = 0; j < 12; j++) { v[j] = xr[lane + 64 * j]; s += v[j]; }
    #pragma unroll
    for (int o = 32; o > 0; o >>= 1) s += __shfl_xor(s, o);
    float mean = s * (1.f / 768.f);
    float q = 0.f;
    #pragma unroll
    for (int j = 0; j < 12; j++) { float d = v[j] - mean; q += d * d; }
    #pragma unroll
    for (int o = 32; o > 0; o >>= 1) q += __shfl_xor(q, o);
    float inv = rsqrtf(q * (1.f / 768.f) + 1e-6f);
    #pragma unroll
    for (int j = 0; j < 12; j++) {
        int c = lane + 64 * j;
        out[c] = f2bf((v[j] - mean) * inv * g[c] + b[c]);
    }
}

// ---------------- LN2 ----------------
__global__ __launch_bounds__(256) void ln2_kernel(
        const float* __restrict__ y, const float* __restrict__ g,
        const float* __restrict__ b, unsigned short* __restrict__ h2) {
    int tid = threadIdx.x;
    int row = blockIdx.x * 4 + (tid >> 6);
    int lane = tid & 63;
    const float* xr = y + (size_t)row * DIMC;
    float v[12], s = 0.f;
    #pragma unroll
    for (int j = 0; j < 12; j++) { v[j] = xr[lane + 64 * j]; s += v[j]; }
    #pragma unroll
    for (int o = 32; o > 0; o >>= 1) s += __shfl_xor(s, o);
    float mean = s * (1.f / 768.f);
    float q = 0.f;
    #pragma unroll
    for (int j = 0; j < 12; j++) { float d = v[j] - mean; q += d * d; }
    #pragma unroll
    for (int o = 32; o > 0; o >>= 1) q += __shfl_xor(q, o);
    float inv = rsqrtf(q * (1.f / 768.f) + 1e-6f);
    unsigned short* out = h2 + (size_t)row * DIMC;
    #pragma unroll
    for (int j = 0; j < 12; j++) {
        int c = lane + 64 * j;
        out[c] = f2bf((v[j] - mean) * inv * g[c] + b[c]);
    }
}

// ---------------- build A_aug (q | relh | relw | 0) and Vt per (win,head) ----
// rel dots via MFMA: dots[i][r] = q[i] . RT[r], RT = [relph(27) | relpw(27)].
// relh[i][c] = dots[i][13 + i/14 - c]; relw[i][c] = dots[i][27 + 13 + i%14 - c].
__global__ __launch_bounds__(256) void build_aug(
        const unsigned short* __restrict__ qkvb,
        const float* __restrict__ relph, const float* __restrict__ relpw,
        unsigned short* __restrict__ Aaug, unsigned short* __restrict__ Vt) {
    __shared__ unsigned short qs[208 * 72];   // pitch 72: b128-aligned, 2-way banks
    __shared__ unsigned short rt[64 * 72];
    int tid = threadIdx.x;
    int bh = blockIdx.x, w = bh / HEADS, head = bh % HEADS;
    int lane = tid & 63, wave = tid >> 6;
    int l15 = lane & 15, q4 = lane >> 4, q8 = q4 * 8;
    size_t base = (size_t)w * NTOK * 2304 + head * 64;
    unsigned short* ab = Aaug + (size_t)bh * 256 * 96;

    // stage q -> qs, copy to ab cols 0..63
    for (int e = tid; e < 196 * 8; e += 256) {
        int t = e >> 3, s8 = (e & 7) * 8;
        bf16x8 qv = *(const bf16x8*)&qkvb[base + (size_t)t * 2304 + s8];
        *(bf16x8*)&qs[t * 72 + s8] = qv;
        *(bf16x8*)&ab[t * 96 + s8] = qv;
    }
    for (int e = tid; e < 12 * 8; e += 256) {  // zero qs rows 196..207
        bf16x8 z = {};
        *(bf16x8*)&qs[(196 + (e >> 3)) * 72 + (e & 7) * 8] = z;
    }
    // stage RT tables (f32 -> bf16), rows 54..63 zero
    for (int e = tid; e < 64 * 8; e += 256) {
        int r = e >> 3, s8 = (e & 7) * 8;
        bf16x8 ov = {};
        if (r < 54) {
            const float* src = (r < 27 ? relph + (size_t)r * 64
                                       : relpw + (size_t)(r - 27) * 64) + s8;
            #pragma unroll
            for (int jj = 0; jj < 8; jj++) ov[jj] = (short)f2bf(src[jj]);
        }
        *(bf16x8*)&rt[r * 72 + s8] = ov;
    }
    // zero ab rows 196..255 (all 96 cols) and cols 92..95
    for (int e = tid; e < 60 * 12; e += 256) {
        bf16x8 z = {};
        *(bf16x8*)&ab[(size_t)(196 + e / 12) * 96 + (e % 12) * 8] = z;
    }
    for (int e = tid; e < 196; e += 256) {
        ab[e * 96 + 92] = 0; ab[e * 96 + 93] = 0;
        ab[e * 96 + 94] = 0; ab[e * 96 + 95] = 0;
    }
    __syncthreads();

    // rel MFMA + scatter into ab cols 64..91
    #pragma unroll
    for (int t = 0; t < 4; t++) {
        int it = wave * 4 + t;
        if (it >= 13) break;                      // wave-uniform
        bf16x8 a0 = *(bf16x8*)&qs[(it * 16 + l15) * 72 + q8];
        bf16x8 a1 = *(bf16x8*)&qs[(it * 16 + l15) * 72 + 32 + q8];
        #pragma unroll
        for (int rt4 = 0; rt4 < 4; rt4++) {
            bf16x8 b0 = *(bf16x8*)&rt[(rt4 * 16 + l15) * 72 + q8];
            bf16x8 b1 = *(bf16x8*)&rt[(rt4 * 16 + l15) * 72 + 32 + q8];
            f32x4 d4 = {};
            d4 = __builtin_amdgcn_mfma_f32_16x16x32_bf16(a0, b0, d4, 0, 0, 0);
            d4 = __builtin_amdgcn_mfma_f32_16x16x32_bf16(a1, b1, d4, 0, 0, 0);
            int rcol = rt4 * 16 + l15;
            #pragma unroll
            for (int r = 0; r < 4; r++) {
                int i = it * 16 + q4 * 4 + r;
                if (i < 196 && rcol < 54) {
                    if (rcol < 27) {
                        int c = 13 + i / 14 - rcol;
                        if (c >= 0 && c < 14) ab[i * 96 + 64 + c] = f2bf(d4[r]);
                    } else {
                        int c = 13 + i % 14 - (rcol - 27);
                        if (c >= 0 && c < 14) ab[i * 96 + 78 + c] = f2bf(d4[r]);
                    }
                }
            }
        }
    }

    // Vt[d][224]: vector read V, scalar global scatter (L2 write-combines)
    unsigned short* vtb = Vt + (size_t)bh * 64 * 224;
    for (int e = tid; e < 196 * 8; e += 256) {
        int j = e >> 3, dg = (e & 7) * 8;
        bf16x8 vv = *(const bf16x8*)&qkvb[base + 1536 + (size_t)j * 2304 + dg];
        #pragma unroll
        for (int k = 0; k < 8; k++)
            vtb[(size_t)(dg + k) * 224 + j] = (unsigned short)vv[k];
    }
    for (int e = tid; e < 64 * 28; e += 256)     // zero cols 196..223
        vtb[(size_t)(e / 28) * 224 + 196 + (e % 28)] = 0;
}

// ---------------- fused MFMA attention: one block per (window,head) --------
__global__ __launch_bounds__(256) void attn_mfma(
        const unsigned short* __restrict__ qkvb,
        const unsigned short* __restrict__ Aaug,
        const unsigned short* __restrict__ Vt,
        unsigned short* __restrict__ out) {
    __shared__ unsigned short Kls[208 * 96];   // K_aug: [k*0.125 | oh(j/14) | oh(j%14) | 0]
    __shared__ unsigned short Pls[4][64 * 40]; // per-wave P strip, pitch 40
    int tid = threadIdx.x;
    int bh = blockIdx.x, w = bh / HEADS, head = bh % HEADS;
    int wave = tid >> 6, lane = tid & 63;
    int l15 = lane & 15, q4 = lane >> 4, q8 = q4 * 8;
    size_t kbase = (size_t)w * NTOK * 2304 + head * 64 + 768;
    // stage K*0.125 (exact: pow2) rows 0..195
    for (int e = tid; e < 196 * 8; e += 256) {
        int t = e >> 3, s8 = (e & 7) * 8;
        bf16x8 kv = *(const bf16x8*)&qkvb[kbase + (size_t)t * 2304 + s8];
        bf16x8 ko;
        #pragma unroll
        for (int jj = 0; jj < 8; jj++)
            ko[jj] = (short)f2bf(bf2f((unsigned short)kv[jj]) * 0.125f);
        *(bf16x8*)&Kls[t * 96 + s8] = ko;
    }
    bf16x8 z8 = {};
    for (int e = tid; e < 208 * 4; e += 256)   // zero cols 64..95
        *(bf16x8*)&Kls[(e >> 2) * 96 + 64 + (e & 3) * 8] = z8;
    for (int e = tid; e < 12 * 8; e += 256)    // zero rows 196..207 cols 0..63
        *(bf16x8*)&Kls[(196 + (e >> 3)) * 96 + (e & 7) * 8] = z8;
    __syncthreads();                           // zeros before one-hots (same dwords)
    for (int e = tid; e < 196; e += 256) {
        Kls[e * 96 + 64 + e / WIN] = 0x3F80;   // bf16(1.0)
        Kls[e * 96 + 78 + e % WIN] = 0x3F80;
    }
    // A-frags from global (held in regs across all j-tiles)
    bf16x8 af[4][3];
    const unsigned short* abse = Aaug + (size_t)bh * 256 * 96;
    #pragma unroll
    for (int it = 0; it < 4; it++)
        #pragma unroll
        for (int c = 0; c < 3; c++)
            af[it][c] = *(const bf16x8*)&abse[(size_t)(wave * 64 + it * 16 + l15) * 96 + c * 32 + q8];
    __syncthreads();                           // K_aug complete

    const unsigned short* vtb = Vt + (size_t)bh * 64 * 224;
    f32x4 o[4][4] = {};
    float lacc[4][4] = {{0.f}};
    bf16x8 bv[4];
    #pragma unroll
    for (int dt = 0; dt < 4; dt++)
        bv[dt] = *(const bf16x8*)&vtb[(dt * 16 + l15) * 224 + q8];

    for (int jp = 0; jp < 7; jp++) {
        f32x4 s[4][2] = {};
        #pragma unroll
        for (int half = 0; half < 2; half++) {
            int jt = jp * 2 + half;
            if (jt < 13) {
                #pragma unroll
                for (int c = 0; c < 3; c++) {
                    bf16x8 bk = *(bf16x8*)&Kls[(jt * 16 + l15) * 96 + c * 32 + q8];
                    #pragma unroll
                    for (int it = 0; it < 4; it++)
                        s[it][half] = __builtin_amdgcn_mfma_f32_16x16x32_bf16(
                            af[it][c], bk, s[it][half], 0, 0, 0);
                }
            }
        }
        __syncthreads();   // WAR: previous PV reads of Pls complete
        #pragma unroll
        for (int half = 0; half < 2; half++) {
            int jt = jp * 2 + half;
            bool valid = (jt < 13) && (jt * 16 + l15) < 196;
            #pragma unroll
            for (int it = 0; it < 4; it++)
                #pragma unroll
                for (int r = 0; r < 4; r++) {
                    float p = valid ? __expf(s[it][half][r]) : 0.f;
                    unsigned short pb = f2bf(p);
                    lacc[it][r] += bf2f(pb);
                    Pls[wave][(it * 16 + q4 * 4 + r) * 40 + half * 16 + l15] = pb;
                }
        }
        __syncthreads();   // RAW: P visible
        bf16x8 ap[4];
        #pragma unroll
        for (int it = 0; it < 4; it++)
            ap[it] = *(bf16x8*)&Pls[wave][(it * 16 + l15) * 40 + q8];
        bf16x8 bvn[4];
        if (jp < 6) {
            #pragma unroll
            for (int dt = 0; dt < 4; dt++)
                bvn[dt] = *(const bf16x8*)&vtb[(dt * 16 + l15) * 224 + (jp + 1) * 32 + q8];
        }
        #pragma unroll
        for (int dt = 0; dt < 4; dt++)
            #pragma unroll
            for (int it = 0; it < 4; it++)
                o[it][dt] = __builtin_amdgcn_mfma_f32_16x16x32_bf16(
                    ap[it], bv[dt], o[it][dt], 0, 0, 0);
        if (jp < 6) {
            #pragma unroll
            for (int dt = 0; dt < 4; dt++) bv[dt] = bvn[dt];
        }
    }
    // row sums across the 16 j-lanes of each quad
    #pragma unroll
    for (int it = 0; it < 4; it++)
        #pragma unroll
        for (int r = 0; r < 4; r++) {
            float v = lacc[it][r];
            v += __shfl_xor(v, 1); v += __shfl_xor(v, 2);
            v += __shfl_xor(v, 4); v += __shfl_xor(v, 8);
            lacc[it][r] = 1.f / v;
        }
    // store O (win, token, head, d)
    #pragma unroll
    for (int it = 0; it < 4; it++) {
        int i0 = wave * 64 + it * 16 + q4 * 4;
        #pragma unroll
        for (int r = 0; r < 4; r++) {
            if (i0 + r < 196) {
                size_t rowb = (size_t)(w * NTOK + i0 + r) * DIMC + head * 64;
                #pragma unroll
                for (int dt = 0; dt < 4; dt++)
                    out[rowb + dt * 16 + l15] = f2bf(o[it][dt][r] * lacc[it][r]);
            }
        }
    }
}

// ---------------- 8-phase MFMA GEMM, BM=BN=256, BK=64, 512 threads ----------
// 8 waves 2Mx4N, per-wave 128x64 (acc[8][4]). LDS 128KB: A/B each
// [dbuf][khalf][256 rows][32 shorts]. Per tile t (dbuf t&1), 4 phases:
//   Q=0:(h0,mi0-3) Q=1:(h0,mi4-7) Q=2:(h1,mi0-3) Q=3:(h1,mi4-7), all ni.
// Phase (t,Q): 8 ds_read_b128 -> stage unit Q of tile t+1 (Q=0:Ah0 1:Bh0
// 2:Ah1 3:Bh1; dbuf (t+1)&1 so never the read buffer) -> vmcnt at odd Q
// (steady 4 = last 2 units in flight; guarantees units needed by the next
// 2 phases landed; barrier publishes every wave's own vmcnt) -> barrier ->
// setprio(1) 16 MFMA setprio(0) -> barrier. Units get 3-4 phases to land.
// Frag swizzle: LDS[row][s] holds global seg s^((row>>1)&3); a wave's
// ds_read_b128 then covers a contiguous 1KB block (conflict-free).
template <int EPI>
__global__ __launch_bounds__(512) void mgemm8(
        const unsigned short* __restrict__ A, const unsigned short* __restrict__ Bt,
        const float* __restrict__ bias, void* __restrict__ Cout,
        int M, int Nn, int K, int nbx, int nby) {
    __shared__ unsigned short AsF[2 * 2 * 8192];   // 64KB
    __shared__ unsigned short BsF[2 * 2 * 8192];   // 64KB
    int tid = threadIdx.x;
    int lane = tid & 63, wave = tid >> 6;
    int l15 = lane & 15, q4 = lane >> 4;
    // ---- XCD swizzle ----
    int id = blockIdx.x;
    int per = nbx * 8;
    int s = id / per;
    int rem = id - s * per;
    int rmax = nby - s * 8; if (rmax > 8) rmax = 8;
    int bx = rem / rmax;
    int r_ = rem - bx * rmax;
    int by = s * 8 + r_;
    int m0 = by << 8, n0 = bx << 8;
    int wm = (wave >> 2) << 7;           // 0 / 128
    int wn = (wave & 3) << 6;            // 0,64,128,192
    // frag offsets within one [256x32] khalf plane (shorts); key (l15>>1)&3
    int fseg = (q4 ^ ((l15 >> 1) & 3)) * 8;
    int pa[8], pb[4];
    #pragma unroll
    for (int i = 0; i < 8; i++) pa[i] = (wm + i * 16 + l15) * 32 + fseg;
    #pragma unroll
    for (int i = 0; i < 4; i++) pb[i] = (wn + i * 16 + l15) * 32 + fseg;
    // staging: thread -> (row tid>>2 [+128], seg (tid&3)^((tid>>3)&3))
    int srow = tid >> 2;
    int sseg = ((tid & 3) ^ ((tid >> 3) & 3)) * 8;
    int ra0 = m0 + srow;        if (ra0 >= M) ra0 = M - 1;   // clamp, never stored
    int ra1 = m0 + 128 + srow;  if (ra1 >= M) ra1 = M - 1;
    const unsigned short* gA0 = A + (size_t)ra0 * K + sseg;
    const unsigned short* gA1 = A + (size_t)ra1 * K + sseg;
    const unsigned short* gB0 = Bt + (size_t)(n0 + srow) * K + sseg;
    const unsigned short* gB1 = Bt + (size_t)(n0 + 128 + srow) * K + sseg;
    int ld = tid * 8;                    // pass0 dst (shorts); pass1: +4096
    f32x4 acc[8][4] = {};
    int NT = K >> 6;
    // prologue: tile 0 -> dbuf 0 (Ah0, Bh0, Ah1, Bh1)
    gl2lds16(gA0,      &AsF[ld]);        gl2lds16(gA1,      &AsF[4096 + ld]);
    gl2lds16(gB0,      &BsF[ld]);        gl2lds16(gB1,      &BsF[4096 + ld]);
    gl2lds16(gA0 + 32, &AsF[8192 + ld]); gl2lds16(gA1 + 32, &AsF[8192 + 4096 + ld]);
    gl2lds16(gB0 + 32, &BsF[8192 + ld]); gl2lds16(gB1 + 32, &BsF[8192 + 4096 + ld]);
    asm volatile("s_waitcnt vmcnt(0)" ::: "memory");
    __builtin_amdgcn_s_barrier();

#define MG8_PHASE(Q)                                                          \
    {                                                                         \
        constexpr int h = (Q) >> 1, m2 = (Q) & 1;                             \
        int hb = ((t & 1) * 2 + h) * 8192;                                    \
        bf16x8 af0 = *(bf16x8*)&AsF[hb + pa[m2 * 4 + 0]];                     \
        bf16x8 af1 = *(bf16x8*)&AsF[hb + pa[m2 * 4 + 1]];                     \
        bf16x8 af2 = *(bf16x8*)&AsF[hb + pa[m2 * 4 + 2]];                     \
        bf16x8 af3 = *(bf16x8*)&AsF[hb + pa[m2 * 4 + 3]];                     \
        bf16x8 bf0 = *(bf16x8*)&BsF[hb + pb[0]];                              \
        bf16x8 bf1 = *(bf16x8*)&BsF[hb + pb[1]];                              \
        bf16x8 bf2 = *(bf16x8*)&BsF[hb + pb[2]];                              \
        bf16x8 bf3 = *(bf16x8*)&BsF[hb + pb[3]];                              \
        if (t + 1 < NT) {                                                     \
            int hb2 = (((t + 1) & 1) * 2 + h) * 8192;                         \
            int go = (t + 1) * 64 + h * 32;                                   \
            if ((Q) & 1) {                                                    \
                gl2lds16(gB0 + go, &BsF[hb2 + ld]);                           \
                gl2lds16(gB1 + go, &BsF[hb2 + 4096 + ld]);                    \
            } else {                                                          \
                gl2lds16(gA0 + go, &AsF[hb2 + ld]);                           \
                gl2lds16(gA1 + go, &AsF[hb2 + 4096 + ld]);                    \
            }                                                                 \
        }                                                                     \
        if ((Q) & 1) {                                                        \
            if (t + 1 < NT) asm volatile("s_waitcnt vmcnt(4)" ::: "memory");  \
            else            asm volatile("s_waitcnt vmcnt(0)" ::: "memory");  \
        }                                                                     \
        __builtin_amdgcn_sched_barrier(0);                                    \
        __builtin_amdgcn_s_barrier();                                         \
        __builtin_amdgcn_s_setprio(1);                                        \
        acc[m2*4+0][0] = __builtin_amdgcn_mfma_f32_16x16x32_bf16(af0, bf0, acc[m2*4+0][0], 0, 0, 0); \
        acc[m2*4+0][1] = __builtin_amdgcn_mfma_f32_16x16x32_bf16(af0, bf1, acc[m2*4+0][1], 0, 0, 0); \
        acc[m2*4+0][2] = __builtin_amdgcn_mfma_f32_16x16x32_bf16(af0, bf2, acc[m2*4+0][2], 0, 0, 0); \
        acc[m2*4+0][3] = __builtin_amdgcn_mfma_f32_16x16x32_bf16(af0, bf3, acc[m2*4+0][3], 0, 0, 0); \
        acc[m2*4+1][0] = __builtin_amdgcn_mfma_f32_16x16x32_bf16(af1, bf0, acc[m2*4+1][0], 0, 0, 0); \
        acc[m2*4+1][1] = __builtin_amdgcn_mfma_f32_16x16x32_bf16(af1, bf1, acc[m2*4+1][1], 0, 0, 0); \
        acc[m2*4+1][2] = __builtin_amdgcn_mfma_f32_16x16x32_bf16(af1, bf2, acc[m2*4+1][2], 0, 0, 0); \
        acc[m2*4+1][3] = __builtin_amdgcn_mfma_f32_16x16x32_bf16(af1, bf3, acc[m2*4+1][3], 0, 0, 0); \
        acc[m2*4+2][0] = __builtin_amdgcn_mfma_f32_16x16x32_bf16(af2, bf0, acc[m2*4+2][0], 0, 0, 0); \
        acc[m2*4+2][1] = __builtin_amdgcn_mfma_f32_16x16x32_bf16(af2, bf1, acc[m2*4+2][1], 0, 0, 0); \
        acc[m2*4+2][2] = __builtin_amdgcn_mfma_f32_16x16x32_bf16(af2, bf2, acc[m2*4+2][2], 0, 0, 0); \
        acc[m2*4+2][3] = __builtin_amdgcn_mfma_f32_16x16x32_bf16(af2, bf3, acc[m2*4+2][3], 0, 0, 0); \
        acc[m2*4+3][0] = __builtin_amdgcn_mfma_f32_16x16x32_bf16(af3, bf0, acc[m2*4+3][0], 0, 0, 0); \
        acc[m2*4+3][1] = __builtin_amdgcn_mfma_f32_16x16x32_bf16(af3, bf1, acc[m2*4+3][1], 0, 0, 0); \
        acc[m2*4+3][2] = __builtin_amdgcn_mfma_f32_16x16x32_bf16(af3, bf2, acc[m2*4+3][2], 0, 0, 0); \
        acc[m2*4+3][3] = __builtin_amdgcn_mfma_f32_16x16x32_bf16(af3, bf3, acc[m2*4+3][3], 0, 0, 0); \
        __builtin_amdgcn_s_setprio(0);                                        \
        __builtin_amdgcn_sched_barrier(0);                                    \
        __builtin_amdgcn_s_barrier();                                         \
    }

    for (int t = 0; t < NT; ++t) {
        MG8_PHASE(0)
        MG8_PHASE(1)
        MG8_PHASE(2)
        MG8_PHASE(3)
    }
#undef MG8_PHASE

    int q4r = q4 * 4;
    #pragma unroll
    for (int mi = 0; mi < 8; mi++) {
        #pragma unroll
        for (int r = 0; r < 4; r++) {
            int row = m0 + wm + mi * 16 + q4r + r;
            if (row >= M) continue;
            #pragma unroll
            for (int ni = 0; ni < 4; ni++) {
                int col = n0 + wn + ni * 16 + l15;
                float v = acc[mi][ni][r] + bias[col];
                if (EPI == 1) v = fast_gelu(v);
                ((unsigned short*)Cout)[(size_t)row * Nn + col] = f2bf(v);
            }
        }
    }
}

// ---------------- MFMA GEMM (R10: 3-buffer 2-ahead counted vmcnt), BM=128 ---
// EPI 2: window-unpartition + x residual (f32)   EPI 3: + resid (f32)
template <int EPI, int BN>
__global__ __launch_bounds__(256) void mgemm(
        const unsigned short* __restrict__ A, const unsigned short* __restrict__ Bt,
        const float* __restrict__ bias, void* __restrict__ Cout,
        const float* __restrict__ resid, int M, int Nn, int K,
        int nbx, int nby) {
    const int NI = BN / 32;                 // per-wave n-frags
    constexpr int LPT = (BN == 128) ? 4 : 3;  // gl2lds16 per thread per tile
    __shared__ unsigned short As[3][128 * 32];
    __shared__ unsigned short Bs[3][BN * 32];
    int tid = threadIdx.x;
    int lane = tid & 63, wave = tid >> 6;
    int l15 = lane & 15, q4 = lane >> 4;
    int xq8 = (q4 ^ ((l15 >> 1) & 3)) * 8;  // swizzled frag segment (shorts)
    // ---- XCD swizzle ----
    int id = blockIdx.x;
    int per = nbx * 8;
    int s = id / per;
    int rem = id - s * per;
    int rmax = nby - s * 8; if (rmax > 8) rmax = 8;
    int bx = rem / rmax;
    int r_ = rem - bx * rmax;
    int by = s * 8 + r_;
    int m0 = by << 7, n0 = bx * BN;
    int wm = (wave >> 1) * 64, wn = (wave & 1) * (BN / 2);
    // staging: lane i -> row i/4, swizzled global seg; LDS dst = base + lane*16
    int srow0 = wave * 32 + (lane >> 2);
    int srow1 = srow0 + 16;
    int sseg = ((lane & 3) ^ ((lane >> 3) & 3)) * 8;   // shorts
    int rmA0 = m0 + srow0; if (rmA0 >= M) rmA0 = M - 1;   // clamp: rows>=M never stored
    int rmA1 = m0 + srow1; if (rmA1 >= M) rmA1 = M - 1;
    const unsigned short* gA0 = A + (size_t)rmA0 * K + sseg;
    const unsigned short* gA1 = A + (size_t)rmA1 * K + sseg;
    int browB = (BN == 128) ? srow0 : (wave * 16 + (lane >> 2));
    const unsigned short* gB0 = Bt + (size_t)(n0 + browB) * K + sseg;
    const unsigned short* gB1 = Bt + (size_t)(n0 + srow1) * K + sseg;  // BN=128 only
    int lofsA = wave * 1024 + lane * 8;
    int lofsB = ((BN == 128) ? wave * 1024 : wave * 512) + lane * 8;
    f32x4 acc[4][NI] = {};
    int nt = K >> 5;
    // prologue: stage tiles 0,1 into bufs 0,1 (issue order defines vmcnt FIFO)
    gl2lds16(gA0, &As[0][lofsA]);
    gl2lds16(gA1, &As[0][lofsA + 512]);
    gl2lds16(gB0, &Bs[0][lofsB]);
    if (BN == 128) gl2lds16(gB1, &Bs[0][lofsB + 512]);
    if (nt > 1) {
        gl2lds16(gA0 + 32, &As[1][lofsA]);
        gl2lds16(gA1 + 32, &As[1][lofsA + 512]);
        gl2lds16(gB0 + 32, &Bs[1][lofsB]);
        if (BN == 128) gl2lds16(gB1 + 32, &Bs[1][lofsB + 512]);
    }
    int cur = 0;
    for (int t = 0; t < nt; ++t) {
        if (t + 1 < nt) {
            // drain tile t only; tile t+1 (LPT loads) stays in flight
            asm volatile("s_waitcnt vmcnt(%0)" :: "i"(LPT) : "memory");
        } else {
            asm volatile("s_waitcnt vmcnt(0)" ::: "memory");
        }
        __builtin_amdgcn_s_barrier();
        if (t + 2 < nt) {                    // issue tile t+2 into freed buffer
            int b2 = cur + 2; if (b2 >= 3) b2 -= 3;
            int kn = (t + 2) << 5;
            gl2lds16(gA0 + kn, &As[b2][lofsA]);
            gl2lds16(gA1 + kn, &As[b2][lofsA + 512]);
            gl2lds16(gB0 + kn, &Bs[b2][lofsB]);
            if (BN == 128) gl2lds16(gB1 + kn, &Bs[b2][lofsB + 512]);
        }
        bf16x8 bfr[NI];
        #pragma unroll
        for (int ni = 0; ni < NI; ni++)
            bfr[ni] = *(bf16x8*)&Bs[cur][(wn + ni * 16 + l15) * 32 + xq8];
        #pragma unroll
        for (int mi = 0; mi < 4; mi++) {
            bf16x8 afr = *(bf16x8*)&As[cur][(wm + mi * 16 + l15) * 32 + xq8];
            #pragma unroll
            for (int ni = 0; ni < NI; ni++)
                acc[mi][ni] = __builtin_amdgcn_mfma_f32_16x16x32_bf16(
                    afr, bfr[ni], acc[mi][ni], 0, 0, 0);
        }
        cur = (cur == 2) ? 0 : cur + 1;
    }
    int q4r = (lane >> 4) * 4;
    #pragma unroll
    for (int mi = 0; mi < 4; mi++) {
        #pragma unroll
        for (int r = 0; r < 4; r++) {
            int row = m0 + wm + mi * 16 + q4r + r;
            if (row >= M) continue;
            if (EPI == 2) {
                int w = row / NTOK, t = row % NTOK;
                int bi = w / 25, wr = w % 25;
                int gy = (wr / 5) * WIN + t / WIN;
                int gx = (wr % 5) * WIN + t % WIN;
                if (gy >= 64 || gx >= 64) continue;
                size_t orow = ((size_t)((bi * 64 + gy) * 64 + gx)) * DIMC;
                #pragma unroll
                for (int ni = 0; ni < NI; ni++) {
                    int col = n0 + wn + ni * 16 + l15;
                    float v = acc[mi][ni][r] + bias[col];
                    ((float*)Cout)[orow + col] = resid[orow + col] + v;
                }
            } else {
                #pragma unroll
                for (int ni = 0; ni < NI; ni++) {
                    int col = n0 + wn + ni * 16 + l15;
                    float v = acc[mi][ni][r] + bias[col];
                    ((float*)Cout)[(size_t)row * Nn + col] =
                        resid[(size_t)row * Nn + col] + v;
                }
            }
        }
    }
}

// ---------------------------------------------------------------------------
extern "C" void kernel_launch(void* const* d_in, const int* in_sizes, int n_in,
                              void* d_out, int out_size, void* d_ws, size_t ws_size,
                              hipStream_t stream) {
    const float* x      = (const float*)d_in[0];
    const float* ln1_g  = (const float*)d_in[1];
    const float* ln1_b  = (const float*)d_in[2];
    const float* qkv_w  = (const float*)d_in[3];
    const float* qkv_b  = (const float*)d_in[4];
    const float* proj_w = (const float*)d_in[5];
    const float* proj_b = (const float*)d_in[6];
    const float* rel_h  = (const float*)d_in[7];
    const float* rel_w  = (const float*)d_in[8];
    const float* ln2_g  = (const float*)d_in[9];
    const float* ln2_b  = (const float*)d_in[10];
    const float* fc1_w  = (const float*)d_in[11];
    const float* fc1_b  = (const float*)d_in[12];
    const float* fc2_w  = (const float*)d_in[13];
    const float* fc2_b  = (const float*)d_in[14];
    float* out = (float*)d_out;
    char* ws = (char*)d_ws;

    // Workspace regions (max 121,061,376 B), liveness-checked (same as R3-R13):
    unsigned short* wt_qkv  = (unsigned short*)(ws);
    unsigned short* wt_proj = (unsigned short*)(ws + 3538944);
    unsigned short* wt_fc1  = (unsigned short*)(ws + 4718592);
    unsigned short* wt_fc2  = (unsigned short*)(ws + 9437184);
    unsigned short* qkvb    = (unsigned short*)(ws + 14155776);
    float*          yb      = (float*)        (ws + 14155776);
    unsigned short* h2      = (unsigned short*)(ws + 39321600);
    unsigned short* h1      = (unsigned short*)(ws + 59314176);
    unsigned short* attn_o  = h1;
    unsigned short* zb      = h1;
    unsigned short* Aaug    = (unsigned short*)(ws + 74366976);
    unsigned short* Vt      = (unsigned short*)(ws + 103858176);

    transpose_all<<<1728, 256, 0, stream>>>(
        qkv_w, wt_qkv, proj_w, wt_proj, fc1_w, wt_fc1, fc2_w, wt_fc2);

    ln1_win_kernel<<<(MROWS + 3) / 4, 256, 0, stream>>>(x, ln1_g, ln1_b, h1);

    // qkv: M=9800 (nby=39), N=2304 (nbx=9), K=768, 8-phase 256^2
    mgemm8<0><<<9 * 39, 512, 0, stream>>>(
        h1, wt_qkv, qkv_b, qkvb, MROWS, 2304, DIMC, 9, 39);

    build_aug<<<NWIN * HEADS, 256, 0, stream>>>(qkvb, rel_h, rel_w, Aaug, Vt);

    attn_mfma<<<NWIN * HEADS, 256, 0, stream>>>(qkvb, Aaug, Vt, attn_o);

    // proj: M=9800 (nby=77), N=768 (nbx=12 @BN=64), K=768  (R10 config)
    mgemm<2, 64><<<12 * 77, 256, 0, stream>>>(
        attn_o, wt_proj, proj_b, yb, x, MROWS, DIMC, DIMC, 12, 77);

    ln2_kernel<<<YROWS / 4, 256, 0, stream>>>(yb, ln2_g, ln2_b, h2);

    // fc1: M=8192 (nby=32), N=3072 (nbx=12), K=768, 8-phase 256^2
    mgemm8<1><<<12 * 32, 512, 0, stream>>>(
        h2, wt_fc1, fc1_b, zb, YROWS, MLP_HID, DIMC, 12, 32);

    // fc2: M=8192 (nby=64), N=768 (nbx=12 @BN=64), K=3072  (R10 config)
    mgemm<3, 64><<<12 * 64, 256, 0, stream>>>(
        zb, wt_fc2, fc2_b, out, yb, YROWS, DIMC, MLP_HID, 12, 64);
}

// Round 7
// 456.947 us; speedup vs baseline: 1.1894x; 1.1894x over previous
//
#include <hip/hip_runtime.h>
#include <hip/hip_bf16.h>
#include <math.h>

// ---------------------------------------------------------------------------
// Swin/SAM-style block. R15: (a) GEMMs reverted to the exact R10 config
// (BM=128, BN 128/64, 3-buffer 2-ahead counted vmcnt — best measured 428.7us;
// R11-R14 tile/8-phase experiments all regressed at K=768). (b) attention
// restructured: drop the one-hot rel trick (padded QK^T K 64->96, 49KB/block
// Aaug global round-trip). build_aug now emits only the rel dots table
// (196x54 bf16); attn adds relh+relw during the exp phase via 2 LDS reads
// (ch=13+i/14-j/14, cw=40+i%14-j%14, always in-range for valid j). QK^T
// -33% MFMA, K-staging -33%, Aaug traffic (59MB) eliminated; attn LDS 73.7KB
// keeps 2 blocks/CU.
// ---------------------------------------------------------------------------

#define DIMC 768
#define HEADS 12
#define WIN 14
#define NTOK 196
#define NWIN 50
#define MROWS 9800
#define YROWS 8192
#define MLP_HID 3072

using bf16x8 = __attribute__((ext_vector_type(8))) short;
using f32x4  = __attribute__((ext_vector_type(4))) float;

__device__ __forceinline__ float bf2f(unsigned short u) {
    return __uint_as_float(((unsigned)u) << 16);
}
__device__ __forceinline__ unsigned short f2bf(float f) {
    unsigned u = __float_as_uint(f);
    unsigned r = (u + 0x7fffu + ((u >> 16) & 1u)) >> 16;   // round-nearest-even
    return (unsigned short)r;
}
__device__ __forceinline__ void gl2lds16(const unsigned short* g, unsigned short* l) {
    __builtin_amdgcn_global_load_lds(
        (const __attribute__((address_space(1))) void*)g,
        (__attribute__((address_space(3))) void*)l, 16, 0, 0);
}

// Branchless exact-enough gelu: 0.5*v*(1+erf(v/sqrt(2))).
// erf via Abramowitz-Stegun 7.1.26 (max err 1.5e-7 < bf16 quantum).
__device__ __forceinline__ float fast_gelu(float v) {
    float u = v * 0.70710678118654752f;
    float a = fabsf(u);
    float t = __builtin_amdgcn_rcpf(fmaf(0.3275911f, a, 1.0f));
    float p = t * fmaf(t, fmaf(t, fmaf(t, fmaf(t, 1.061405429f, -1.453152027f),
                       1.421413741f), -0.284496736f), 0.254829592f);
    float e = __expf(-u * u);
    float er = fmaf(-p, e, 1.0f);            // erf(|u|)
    er = copysignf(er, v);
    return 0.5f * v * (1.0f + er);
}

// ---------------- fused 4-way weight transpose: W (K x N, f32) -> Wt (N x K, bf16)
// block ranges: [0,432) qkv  [432,576) proj  [576,1152) fc1  [1152,1728) fc2
__global__ __launch_bounds__(256) void transpose_all(
        const float* __restrict__ Wq, unsigned short* __restrict__ Tq,
        const float* __restrict__ Wp, unsigned short* __restrict__ Tp,
        const float* __restrict__ W1, unsigned short* __restrict__ T1,
        const float* __restrict__ W2, unsigned short* __restrict__ T2) {
    int id = blockIdx.x;
    const float* W; unsigned short* Wt; int K, N, nbx, rel;
    if (id < 432)       { W = Wq; Wt = Tq; K = 768;  N = 2304; nbx = 36; rel = id; }
    else if (id < 576)  { W = Wp; Wt = Tp; K = 768;  N = 768;  nbx = 12; rel = id - 432; }
    else if (id < 1152) { W = W1; Wt = T1; K = 768;  N = 3072; nbx = 48; rel = id - 576; }
    else                { W = W2; Wt = T2; K = 3072; N = 768;  nbx = 12; rel = id - 1152; }
    int bx = rel % nbx, by = rel / nbx;
    __shared__ float t[64][65];
    int k0 = by << 6, n0 = bx << 6;
    int tn = threadIdx.x & 63;
    int tk = threadIdx.x >> 6;
    #pragma unroll
    for (int r = 0; r < 16; r++) {
        int k = tk + r * 4;
        t[k][tn] = W[(size_t)(k0 + k) * N + n0 + tn];
    }
    __syncthreads();
    #pragma unroll
    for (int r = 0; r < 16; r++) {
        int n = tk + r * 4;
        Wt[(size_t)(n0 + n) * K + k0 + tn] = f2bf(t[tn][n]);
    }
}

// ---------------- LN1 + window partition (zeros in padding) ----------------
__global__ __launch_bounds__(256) void ln1_win_kernel(
        const float* __restrict__ x, const float* __restrict__ g,
        const float* __restrict__ b, unsigned short* __restrict__ h1) {
    int tid = threadIdx.x;
    int row = blockIdx.x * 4 + (tid >> 6);
    int lane = tid & 63;
    if (row >= MROWS) return;
    int w = row / NTOK, t = row % NTOK;
    int bi = w / 25, wr = w % 25;
    int gy = (wr / 5) * WIN + t / WIN;
    int gx = (wr % 5) * WIN + t % WIN;
    unsigned short* out = h1 + (size_t)row * DIMC;
    if (gy >= 64 || gx >= 64) {           // reference pads AFTER LN -> zeros
        #pragma unroll
        for (int j = 0; j < 12; j++) out[lane + 64 * j] = 0;
        return;
    }
    const float* xr = x + ((size_t)((bi * 64 + gy) * 64 + gx)) * DIMC;
    float v[12], s = 0.f;
    #pragma unroll
    for (int j = 0; j < 12; j++) { v[j] = xr[lane + 64 * j]; s += v[j]; }
    #pragma unroll
    for (int o = 32; o > 0; o >>= 1) s += __shfl_xor(s, o);
    float mean = s * (1.f / 768.f);
    float q = 0.f;
    #pragma unroll
    for (int j = 0; j < 12; j++) { float d = v[j] - mean; q += d * d; }
    #pragma unroll
    for (int o = 32; o > 0; o >>= 1) q += __shfl_xor(q, o);
    float inv = rsqrtf(q * (1.f / 768.f) + 1e-6f);
    #pragma unroll
    for (int j = 0; j < 12; j++) {
        int c = lane + 64 * j;
        out[c] = f2bf((v[j] - mean) * inv * g[c] + b[c]);
    }
}

// ---------------- LN2 ----------------
__global__ __launch_bounds__(256) void ln2_kernel(
        const float* __restrict__ y, const float* __restrict__ g,
        const float* __restrict__ b, unsigned short* __restrict__ h2) {
    int tid = threadIdx.x;
    int row = blockIdx.x * 4 + (tid >> 6);
    int lane = tid & 63;
    const float* xr = y + (size_t)row * DIMC;
    float v[12], s = 0.f;
    #pragma unroll
    for (int j = 0; j < 12; j++) { v[j] = xr[lane + 64 * j]; s += v[j]; }
    #pragma unroll
    for (int o = 32; o > 0; o >>= 1) s += __shfl_xor(s, o);
    float mean = s * (1.f / 768.f);
    float q = 0.f;
    #pragma unroll
    for (int j = 0; j < 12; j++) { float d = v[j] - mean; q += d * d; }
    #pragma unroll
    for (int o = 32; o > 0; o >>= 1) q += __shfl_xor(q, o);
    float inv = rsqrtf(q * (1.f / 768.f) + 1e-6f);
    unsigned short* out = h2 + (size_t)row * DIMC;
    #pragma unroll
    for (int j = 0; j < 12; j++) {
        int c = lane + 64 * j;
        out[c] = f2bf((v[j] - mean) * inv * g[c] + b[c]);
    }
}

// ---------------- build rel-dots table and Vt per (win,head) ---------------
// dots[i][r] = q[i] . RT[r], RT = [relph(27) | relpw(27)], bf16, laid out
// [208 rows][56 cols] (rows 196..207 and cols 54..55 zeroed).
__global__ __launch_bounds__(256) void build_aug(
        const unsigned short* __restrict__ qkvb,
        const float* __restrict__ relph, const float* __restrict__ relpw,
        unsigned short* __restrict__ dots_g, unsigned short* __restrict__ Vt) {
    __shared__ unsigned short qs[208 * 72];   // pitch 72: b128-aligned, 2-way banks
    __shared__ unsigned short rt[64 * 72];
    int tid = threadIdx.x;
    int bh = blockIdx.x, w = bh / HEADS, head = bh % HEADS;
    int lane = tid & 63, wave = tid >> 6;
    int l15 = lane & 15, q4 = lane >> 4, q8 = q4 * 8;
    size_t base = (size_t)w * NTOK * 2304 + head * 64;

    // stage q -> qs
    for (int e = tid; e < 196 * 8; e += 256) {
        int t = e >> 3, s8 = (e & 7) * 8;
        bf16x8 qv = *(const bf16x8*)&qkvb[base + (size_t)t * 2304 + s8];
        *(bf16x8*)&qs[t * 72 + s8] = qv;
    }
    for (int e = tid; e < 12 * 8; e += 256) {  // zero qs rows 196..207
        bf16x8 z = {};
        *(bf16x8*)&qs[(196 + (e >> 3)) * 72 + (e & 7) * 8] = z;
    }
    // stage RT tables (f32 -> bf16), rows 54..63 zero
    for (int e = tid; e < 64 * 8; e += 256) {
        int r = e >> 3, s8 = (e & 7) * 8;
        bf16x8 ov = {};
        if (r < 54) {
            const float* src = (r < 27 ? relph + (size_t)r * 64
                                       : relpw + (size_t)(r - 27) * 64) + s8;
            #pragma unroll
            for (int jj = 0; jj < 8; jj++) ov[jj] = (short)f2bf(src[jj]);
        }
        *(bf16x8*)&rt[r * 72 + s8] = ov;
    }
    __syncthreads();

    // rel MFMA -> dots_g (C-layout scatter; covers all 208x56 incl. zeros)
    unsigned short* db = dots_g + (size_t)bh * 208 * 56;
    #pragma unroll
    for (int t = 0; t < 4; t++) {
        int it = wave * 4 + t;
        if (it >= 13) break;                      // wave-uniform
        bf16x8 a0 = *(bf16x8*)&qs[(it * 16 + l15) * 72 + q8];
        bf16x8 a1 = *(bf16x8*)&qs[(it * 16 + l15) * 72 + 32 + q8];
        #pragma unroll
        for (int rt4 = 0; rt4 < 4; rt4++) {
            bf16x8 b0 = *(bf16x8*)&rt[(rt4 * 16 + l15) * 72 + q8];
            bf16x8 b1 = *(bf16x8*)&rt[(rt4 * 16 + l15) * 72 + 32 + q8];
            f32x4 d4 = {};
            d4 = __builtin_amdgcn_mfma_f32_16x16x32_bf16(a0, b0, d4, 0, 0, 0);
            d4 = __builtin_amdgcn_mfma_f32_16x16x32_bf16(a1, b1, d4, 0, 0, 0);
            int rcol = rt4 * 16 + l15;
            #pragma unroll
            for (int r = 0; r < 4; r++) {
                int i = it * 16 + q4 * 4 + r;     // <= 207
                if (rcol < 56)
                    db[i * 56 + rcol] =
                        (i < 196 && rcol < 54) ? f2bf(d4[r]) : (unsigned short)0;
            }
        }
    }

    // Vt[d][224]: vector read V, scalar global scatter (L2 write-combines)
    unsigned short* vtb = Vt + (size_t)bh * 64 * 224;
    for (int e = tid; e < 196 * 8; e += 256) {
        int j = e >> 3, dg = (e & 7) * 8;
        bf16x8 vv = *(const bf16x8*)&qkvb[base + 1536 + (size_t)j * 2304 + dg];
        #pragma unroll
        for (int k = 0; k < 8; k++)
            vtb[(size_t)(dg + k) * 224 + j] = (unsigned short)vv[k];
    }
    for (int e = tid; e < 64 * 28; e += 256)     // zero cols 196..223
        vtb[(size_t)(e / 28) * 224 + 196 + (e % 28)] = 0;
}

// ---------------- fused MFMA attention: one block per (window,head) --------
// QK^T over K=64 only; rel added in the exp phase from the LDS dots table:
// score(i,j) += dots[i][13 + i/14 - j/14] + dots[i][40 + i%14 - j%14].
__global__ __launch_bounds__(256) void attn_mfma(
        const unsigned short* __restrict__ qkvb,
        const unsigned short* __restrict__ dots_g,
        const unsigned short* __restrict__ Vt,
        unsigned short* __restrict__ out) {
    __shared__ unsigned short Kls[208 * 72];   // K*0.125, pitch 72
    __shared__ unsigned short Dls[208 * 56];   // rel dots (bf16)
    __shared__ unsigned short Pls[4][64 * 40]; // per-wave P strip, pitch 40
    int tid = threadIdx.x;
    int bh = blockIdx.x, w = bh / HEADS, head = bh % HEADS;
    int wave = tid >> 6, lane = tid & 63;
    int l15 = lane & 15, q4 = lane >> 4, q8 = q4 * 8;
    size_t qbase = (size_t)w * NTOK * 2304 + head * 64;
    size_t kbase = qbase + 768;
    // stage K*0.125 (exact: pow2) rows 0..195
    for (int e = tid; e < 196 * 8; e += 256) {
        int t = e >> 3, s8 = (e & 7) * 8;
        bf16x8 kv = *(const bf16x8*)&qkvb[kbase + (size_t)t * 2304 + s8];
        bf16x8 ko;
        #pragma unroll
        for (int jj = 0; jj < 8; jj++)
            ko[jj] = (short)f2bf(bf2f((unsigned short)kv[jj]) * 0.125f);
        *(bf16x8*)&Kls[t * 72 + s8] = ko;
    }
    bf16x8 z8 = {};
    for (int e = tid; e < 12 * 8; e += 256)    // zero rows 196..207
        *(bf16x8*)&Kls[(196 + (e >> 3)) * 72 + (e & 7) * 8] = z8;
    // stage dots table (208 rows x 7 chunks of 8)
    {
        const unsigned short* dg = dots_g + (size_t)bh * 208 * 56;
        for (int e = tid; e < 208 * 7; e += 256) {
            int row = e / 7, ch = e - row * 7;
            *(bf16x8*)&Dls[row * 56 + ch * 8] = *(const bf16x8*)&dg[row * 56 + ch * 8];
        }
    }
    // A-frags (q) direct from global, row clamped (rows>=196 never stored)
    bf16x8 af[4][2];
    #pragma unroll
    for (int it = 0; it < 4; it++) {
        int arow = wave * 64 + it * 16 + l15;
        if (arow > 195) arow = 195;
        #pragma unroll
        for (int c = 0; c < 2; c++)
            af[it][c] = *(const bf16x8*)&qkvb[qbase + (size_t)arow * 2304 + c * 32 + q8];
    }
    __syncthreads();                           // K,D staged

    const unsigned short* vtb = Vt + (size_t)bh * 64 * 224;
    f32x4 o[4][4] = {};
    float lacc[4][4] = {{0.f}};
    bf16x8 bv[4];
    #pragma unroll
    for (int dt = 0; dt < 4; dt++)
        bv[dt] = *(const bf16x8*)&vtb[(dt * 16 + l15) * 224 + q8];

    for (int jp = 0; jp < 7; jp++) {
        f32x4 s[4][2] = {};
        #pragma unroll
        for (int half = 0; half < 2; half++) {
            int jt = jp * 2 + half;
            if (jt < 13) {
                #pragma unroll
                for (int c = 0; c < 2; c++) {
                    bf16x8 bk = *(bf16x8*)&Kls[(jt * 16 + l15) * 72 + c * 32 + q8];
                    #pragma unroll
                    for (int it = 0; it < 4; it++)
                        s[it][half] = __builtin_amdgcn_mfma_f32_16x16x32_bf16(
                            af[it][c], bk, s[it][half], 0, 0, 0);
                }
            }
        }
        __syncthreads();   // WAR: previous PV reads of Pls complete
        #pragma unroll
        for (int half = 0; half < 2; half++) {
            int jt = jp * 2 + half;
            int j = jt * 16 + l15;
            bool valid = (jt < 13) && (j < 196);
            int jd = (j * 4682) >> 16;         // j/14 for j<=223
            int jm = j - 14 * jd;
            #pragma unroll
            for (int it = 0; it < 4; it++)
                #pragma unroll
                for (int r = 0; r < 4; r++) {
                    int i = it * 16 + q4 * 4 + r;
                    int ii = (i > 195) ? 195 : i;
                    int iid = (ii * 4682) >> 16;
                    int iim = ii - 14 * iid;
                    float rel = bf2f(Dls[ii * 56 + 13 + iid - jd])
                              + bf2f(Dls[ii * 56 + 40 + iim - jm]);
                    float p = valid ? __expf(s[it][half][r] + rel) : 0.f;
                    unsigned short pb = f2bf(p);
                    lacc[it][r] += bf2f(pb);
                    Pls[wave][(it * 16 + q4 * 4 + r) * 40 + half * 16 + l15] = pb;
                }
        }
        __syncthreads();   // RAW: P visible
        bf16x8 ap[4];
        #pragma unroll
        for (int it = 0; it < 4; it++)
            ap[it] = *(bf16x8*)&Pls[wave][(it * 16 + l15) * 40 + q8];
        bf16x8 bvn[4];
        if (jp < 6) {
            #pragma unroll
            for (int dt = 0; dt < 4; dt++)
                bvn[dt] = *(const bf16x8*)&vtb[(dt * 16 + l15) * 224 + (jp + 1) * 32 + q8];
        }
        #pragma unroll
        for (int dt = 0; dt < 4; dt++)
            #pragma unroll
            for (int it = 0; it < 4; it++)
                o[it][dt] = __builtin_amdgcn_mfma_f32_16x16x32_bf16(
                    ap[it], bv[dt], o[it][dt], 0, 0, 0);
        if (jp < 6) {
            #pragma unroll
            for (int dt = 0; dt < 4; dt++) bv[dt] = bvn[dt];
        }
    }
    // row sums across the 16 j-lanes of each quad
    #pragma unroll
    for (int it = 0; it < 4; it++)
        #pragma unroll
        for (int r = 0; r < 4; r++) {
            float v = lacc[it][r];
            v += __shfl_xor(v, 1); v += __shfl_xor(v, 2);
            v += __shfl_xor(v, 4); v += __shfl_xor(v, 8);
            lacc[it][r] = 1.f / v;
        }
    // store O (win, token, head, d)
    #pragma unroll
    for (int it = 0; it < 4; it++) {
        int i0 = wave * 64 + it * 16 + q4 * 4;
        #pragma unroll
        for (int r = 0; r < 4; r++) {
            if (i0 + r < 196) {
                size_t rowb = (size_t)(w * NTOK + i0 + r) * DIMC + head * 64;
                #pragma unroll
                for (int dt = 0; dt < 4; dt++)
                    out[rowb + dt * 16 + l15] = f2bf(o[it][dt][r] * lacc[it][r]);
            }
        }
    }
}

// ---------------- MFMA GEMM (R10: 3-buffer 2-ahead counted vmcnt): ----------
// C = A(MxK bf16) @ Bt(NxK bf16)^T + bias.  BM=128, BN in {128,64}, BK=32.
// Counted vmcnt: barrier at iter t waits only for tile t's loads (vmcnt(LPT)
// leaves tile t+1 in flight); tile t+2 is issued into the buffer freed by
// iter t-1. EPI 0: bf16 store   EPI 1: fast exact-erf gelu -> bf16
// EPI 2: window-unpartition + x residual (f32)   EPI 3: + resid (f32)
template <int EPI, int BN>
__global__ __launch_bounds__(256) void mgemm(
        const unsigned short* __restrict__ A, const unsigned short* __restrict__ Bt,
        const float* __restrict__ bias, void* __restrict__ Cout,
        const float* __restrict__ resid, int M, int Nn, int K,
        int nbx, int nby) {
    const int NI = BN / 32;                 // per-wave n-frags
    constexpr int LPT = (BN == 128) ? 4 : 3;  // gl2lds16 per thread per tile
    __shared__ unsigned short As[3][128 * 32];
    __shared__ unsigned short Bs[3][BN * 32];
    int tid = threadIdx.x;
    int lane = tid & 63, wave = tid >> 6;
    int l15 = lane & 15, q4 = lane >> 4;
    int xq8 = (q4 ^ ((l15 >> 1) & 3)) * 8;  // swizzled frag segment (shorts)
    // ---- XCD swizzle ----
    int id = blockIdx.x;
    int per = nbx * 8;
    int s = id / per;
    int rem = id - s * per;
    int rmax = nby - s * 8; if (rmax > 8) rmax = 8;
    int bx = rem / rmax;
    int r_ = rem - bx * rmax;
    int by = s * 8 + r_;
    int m0 = by << 7, n0 = bx * BN;
    int wm = (wave >> 1) * 64, wn = (wave & 1) * (BN / 2);
    // staging: lane i -> row i/4, swizzled global seg; LDS dst = base + lane*16
    int srow0 = wave * 32 + (lane >> 2);
    int srow1 = srow0 + 16;
    int sseg = ((lane & 3) ^ ((lane >> 3) & 3)) * 8;   // shorts
    int rmA0 = m0 + srow0; if (rmA0 >= M) rmA0 = M - 1;   // clamp: rows>=M never stored
    int rmA1 = m0 + srow1; if (rmA1 >= M) rmA1 = M - 1;
    const unsigned short* gA0 = A + (size_t)rmA0 * K + sseg;
    const unsigned short* gA1 = A + (size_t)rmA1 * K + sseg;
    int browB = (BN == 128) ? srow0 : (wave * 16 + (lane >> 2));
    const unsigned short* gB0 = Bt + (size_t)(n0 + browB) * K + sseg;
    const unsigned short* gB1 = Bt + (size_t)(n0 + srow1) * K + sseg;  // BN=128 only
    int lofsA = wave * 1024 + lane * 8;
    int lofsB = ((BN == 128) ? wave * 1024 : wave * 512) + lane * 8;
    f32x4 acc[4][NI] = {};
    int nt = K >> 5;
    // prologue: stage tiles 0,1 into bufs 0,1 (issue order defines vmcnt FIFO)
    gl2lds16(gA0, &As[0][lofsA]);
    gl2lds16(gA1, &As[0][lofsA + 512]);
    gl2lds16(gB0, &Bs[0][lofsB]);
    if (BN == 128) gl2lds16(gB1, &Bs[0][lofsB + 512]);
    if (nt > 1) {
        gl2lds16(gA0 + 32, &As[1][lofsA]);
        gl2lds16(gA1 + 32, &As[1][lofsA + 512]);
        gl2lds16(gB0 + 32, &Bs[1][lofsB]);
        if (BN == 128) gl2lds16(gB1 + 32, &Bs[1][lofsB + 512]);
    }
    int cur = 0;
    for (int t = 0; t < nt; ++t) {
        if (t + 1 < nt) {
            // drain tile t only; tile t+1 (LPT loads) stays in flight
            asm volatile("s_waitcnt vmcnt(%0)" :: "i"(LPT) : "memory");
        } else {
            asm volatile("s_waitcnt vmcnt(0)" ::: "memory");
        }
        __builtin_amdgcn_s_barrier();
        if (t + 2 < nt) {                    // issue tile t+2 into freed buffer
            int b2 = cur + 2; if (b2 >= 3) b2 -= 3;
            int kn = (t + 2) << 5;
            gl2lds16(gA0 + kn, &As[b2][lofsA]);
            gl2lds16(gA1 + kn, &As[b2][lofsA + 512]);
            gl2lds16(gB0 + kn, &Bs[b2][lofsB]);
            if (BN == 128) gl2lds16(gB1 + kn, &Bs[b2][lofsB + 512]);
        }
        bf16x8 bfr[NI];
        #pragma unroll
        for (int ni = 0; ni < NI; ni++)
            bfr[ni] = *(bf16x8*)&Bs[cur][(wn + ni * 16 + l15) * 32 + xq8];
        #pragma unroll
        for (int mi = 0; mi < 4; mi++) {
            bf16x8 afr = *(bf16x8*)&As[cur][(wm + mi * 16 + l15) * 32 + xq8];
            #pragma unroll
            for (int ni = 0; ni < NI; ni++)
                acc[mi][ni] = __builtin_amdgcn_mfma_f32_16x16x32_bf16(
                    afr, bfr[ni], acc[mi][ni], 0, 0, 0);
        }
        cur = (cur == 2) ? 0 : cur + 1;
    }
    int q4r = (lane >> 4) * 4;
    #pragma unroll
    for (int mi = 0; mi < 4; mi++) {
        #pragma unroll
        for (int r = 0; r < 4; r++) {
            int row = m0 + wm + mi * 16 + q4r + r;
            if (row >= M) continue;
            if (EPI == 2) {
                int w = row / NTOK, t = row % NTOK;
                int bi = w / 25, wr = w % 25;
                int gy = (wr / 5) * WIN + t / WIN;
                int gx = (wr % 5) * WIN + t % WIN;
                if (gy >= 64 || gx >= 64) continue;
                size_t orow = ((size_t)((bi * 64 + gy) * 64 + gx)) * DIMC;
                #pragma unroll
                for (int ni = 0; ni < NI; ni++) {
                    int col = n0 + wn + ni * 16 + l15;
                    float v = acc[mi][ni][r] + bias[col];
                    ((float*)Cout)[orow + col] = resid[orow + col] + v;
                }
            } else {
                #pragma unroll
                for (int ni = 0; ni < NI; ni++) {
                    int col = n0 + wn + ni * 16 + l15;
                    float v = acc[mi][ni][r] + bias[col];
                    if (EPI == 0) {
                        ((unsigned short*)Cout)[(size_t)row * Nn + col] = f2bf(v);
                    } else if (EPI == 1) {
                        v = fast_gelu(v);
                        ((unsigned short*)Cout)[(size_t)row * Nn + col] = f2bf(v);
                    } else {
                        ((float*)Cout)[(size_t)row * Nn + col] =
                            resid[(size_t)row * Nn + col] + v;
                    }
                }
            }
        }
    }
}

// ---------------------------------------------------------------------------
extern "C" void kernel_launch(void* const* d_in, const int* in_sizes, int n_in,
                              void* d_out, int out_size, void* d_ws, size_t ws_size,
                              hipStream_t stream) {
    const float* x      = (const float*)d_in[0];
    const float* ln1_g  = (const float*)d_in[1];
    const float* ln1_b  = (const float*)d_in[2];
    const float* qkv_w  = (const float*)d_in[3];
    const float* qkv_b  = (const float*)d_in[4];
    const float* proj_w = (const float*)d_in[5];
    const float* proj_b = (const float*)d_in[6];
    const float* rel_h  = (const float*)d_in[7];
    const float* rel_w  = (const float*)d_in[8];
    const float* ln2_g  = (const float*)d_in[9];
    const float* ln2_b  = (const float*)d_in[10];
    const float* fc1_w  = (const float*)d_in[11];
    const float* fc1_b  = (const float*)d_in[12];
    const float* fc2_w  = (const float*)d_in[13];
    const float* fc2_b  = (const float*)d_in[14];
    float* out = (float*)d_out;
    char* ws = (char*)d_ws;

    // Workspace regions (max 121,061,376 B), liveness-checked:
    // dots_g replaces Aaug (14.0MB < 29.5MB region).
    unsigned short* wt_qkv  = (unsigned short*)(ws);
    unsigned short* wt_proj = (unsigned short*)(ws + 3538944);
    unsigned short* wt_fc1  = (unsigned short*)(ws + 4718592);
    unsigned short* wt_fc2  = (unsigned short*)(ws + 9437184);
    unsigned short* qkvb    = (unsigned short*)(ws + 14155776);
    float*          yb      = (float*)        (ws + 14155776);
    unsigned short* h2      = (unsigned short*)(ws + 39321600);
    unsigned short* h1      = (unsigned short*)(ws + 59314176);
    unsigned short* attn_o  = h1;
    unsigned short* zb      = h1;
    unsigned short* dots_g  = (unsigned short*)(ws + 74366976);
    unsigned short* Vt      = (unsigned short*)(ws + 103858176);

    transpose_all<<<1728, 256, 0, stream>>>(
        qkv_w, wt_qkv, proj_w, wt_proj, fc1_w, wt_fc1, fc2_w, wt_fc2);

    ln1_win_kernel<<<(MROWS + 3) / 4, 256, 0, stream>>>(x, ln1_g, ln1_b, h1);

    mgemm<0, 128><<<18 * 77, 256, 0, stream>>>(
        h1, wt_qkv, qkv_b, qkvb, nullptr, MROWS, 2304, DIMC, 18, 77);

    build_aug<<<NWIN * HEADS, 256, 0, stream>>>(qkvb, rel_h, rel_w, dots_g, Vt);

    attn_mfma<<<NWIN * HEADS, 256, 0, stream>>>(qkvb, dots_g, Vt, attn_o);

    mgemm<2, 64><<<12 * 77, 256, 0, stream>>>(
        attn_o, wt_proj, proj_b, yb, x, MROWS, DIMC, DIMC, 12, 77);

    ln2_kernel<<<YROWS / 4, 256, 0, stream>>>(yb, ln2_g, ln2_b, h2);

    mgemm<1, 128><<<24 * 64, 256, 0, stream>>>(
        h2, wt_fc1, fc1_b, zb, nullptr, YROWS, MLP_HID, DIMC, 24, 64);

    mgemm<3, 64><<<12 * 64, 256, 0, stream>>>(
        zb, wt_fc2, fc2_b, out, yb, YROWS, DIMC, MLP_HID, 12, 64);
}

// Round 8
// 415.263 us; speedup vs baseline: 1.3088x; 1.1004x over previous
//
#include <hip/hip_runtime.h>
#include <hip/hip_bf16.h>
#include <math.h>

// ---------------------------------------------------------------------------
// Swin/SAM-style block. R16: R10 structure (one-hot rel restored; GEMMs = R10
// exactly) + attn fixes targeting R15's findings (518K bank conflicts, barrier
// overhead): (1) q*0.125 folded into Aaug cols 0..63 (pow2-exact) -> K staging
// is a pure gl2lds copy with pre-swizzled global segs (read XOR-deswizzles by
// l15&7 -> conflict-free b128; was 8-way at pitch 96); one-hots in padded
// Koh[208x40]. (2) Both per-jp block barriers removed -- Pls is per-wave
// (indexed [wave]); intra-wave DS is in-order, one lgkmcnt(0) per jp suffices.
// (3) Pls pitch 40->44: scalar P-writes hit all 32 banks 2-way (free).
// ---------------------------------------------------------------------------

#define DIMC 768
#define HEADS 12
#define WIN 14
#define NTOK 196
#define NWIN 50
#define MROWS 9800
#define YROWS 8192
#define MLP_HID 3072

using bf16x8 = __attribute__((ext_vector_type(8))) short;
using f32x4  = __attribute__((ext_vector_type(4))) float;

__device__ __forceinline__ float bf2f(unsigned short u) {
    return __uint_as_float(((unsigned)u) << 16);
}
__device__ __forceinline__ unsigned short f2bf(float f) {
    unsigned u = __float_as_uint(f);
    unsigned r = (u + 0x7fffu + ((u >> 16) & 1u)) >> 16;   // round-nearest-even
    return (unsigned short)r;
}
__device__ __forceinline__ void gl2lds16(const unsigned short* g, unsigned short* l) {
    __builtin_amdgcn_global_load_lds(
        (const __attribute__((address_space(1))) void*)g,
        (__attribute__((address_space(3))) void*)l, 16, 0, 0);
}

// Branchless exact-enough gelu: 0.5*v*(1+erf(v/sqrt(2))).
// erf via Abramowitz-Stegun 7.1.26 (max err 1.5e-7 < bf16 quantum).
__device__ __forceinline__ float fast_gelu(float v) {
    float u = v * 0.70710678118654752f;
    float a = fabsf(u);
    float t = __builtin_amdgcn_rcpf(fmaf(0.3275911f, a, 1.0f));
    float p = t * fmaf(t, fmaf(t, fmaf(t, fmaf(t, 1.061405429f, -1.453152027f),
                       1.421413741f), -0.284496736f), 0.254829592f);
    float e = __expf(-u * u);
    float er = fmaf(-p, e, 1.0f);            // erf(|u|)
    er = copysignf(er, v);
    return 0.5f * v * (1.0f + er);
}

// ---------------- fused 4-way weight transpose: W (K x N, f32) -> Wt (N x K, bf16)
// block ranges: [0,432) qkv  [432,576) proj  [576,1152) fc1  [1152,1728) fc2
__global__ __launch_bounds__(256) void transpose_all(
        const float* __restrict__ Wq, unsigned short* __restrict__ Tq,
        const float* __restrict__ Wp, unsigned short* __restrict__ Tp,
        const float* __restrict__ W1, unsigned short* __restrict__ T1,
        const float* __restrict__ W2, unsigned short* __restrict__ T2) {
    int id = blockIdx.x;
    const float* W; unsigned short* Wt; int K, N, nbx, rel;
    if (id < 432)       { W = Wq; Wt = Tq; K = 768;  N = 2304; nbx = 36; rel = id; }
    else if (id < 576)  { W = Wp; Wt = Tp; K = 768;  N = 768;  nbx = 12; rel = id - 432; }
    else if (id < 1152) { W = W1; Wt = T1; K = 768;  N = 3072; nbx = 48; rel = id - 576; }
    else                { W = W2; Wt = T2; K = 3072; N = 768;  nbx = 12; rel = id - 1152; }
    int bx = rel % nbx, by = rel / nbx;
    __shared__ float t[64][65];
    int k0 = by << 6, n0 = bx << 6;
    int tn = threadIdx.x & 63;
    int tk = threadIdx.x >> 6;
    #pragma unroll
    for (int r = 0; r < 16; r++) {
        int k = tk + r * 4;
        t[k][tn] = W[(size_t)(k0 + k) * N + n0 + tn];
    }
    __syncthreads();
    #pragma unroll
    for (int r = 0; r < 16; r++) {
        int n = tk + r * 4;
        Wt[(size_t)(n0 + n) * K + k0 + tn] = f2bf(t[tn][n]);
    }
}

// ---------------- LN1 + window partition (zeros in padding) ----------------
__global__ __launch_bounds__(256) void ln1_win_kernel(
        const float* __restrict__ x, const float* __restrict__ g,
        const float* __restrict__ b, unsigned short* __restrict__ h1) {
    int tid = threadIdx.x;
    int row = blockIdx.x * 4 + (tid >> 6);
    int lane = tid & 63;
    if (row >= MROWS) return;
    int w = row / NTOK, t = row % NTOK;
    int bi = w / 25, wr = w % 25;
    int gy = (wr / 5) * WIN + t / WIN;
    int gx = (wr % 5) * WIN + t % WIN;
    unsigned short* out = h1 + (size_t)row * DIMC;
    if (gy >= 64 || gx >= 64) {           // reference pads AFTER LN -> zeros
        #pragma unroll
        for (int j = 0; j < 12; j++) out[lane + 64 * j] = 0;
        return;
    }
    const float* xr = x + ((size_t)((bi * 64 + gy) * 64 + gx)) * DIMC;
    float v[12], s = 0.f;
    #pragma unroll
    for (int j = 0; j < 12; j++) { v[j] = xr[lane + 64 * j]; s += v[j]; }
    #pragma unroll
    for (int o = 32; o > 0; o >>= 1) s += __shfl_xor(s, o);
    float mean = s * (1.f / 768.f);
    float q = 0.f;
    #pragma unroll
    for (int j = 0; j < 12; j++) { float d = v[j] - mean; q += d * d; }
    #pragma unroll
    for (int o = 32; o > 0; o >>= 1) q += __shfl_xor(q, o);
    float inv = rsqrtf(q * (1.f / 768.f) + 1e-6f);
    #pragma unroll
    for (int j = 0; j < 12; j++) {
        int c = lane + 64 * j;
        out[c] = f2bf((v[j] - mean) * inv * g[c] + b[c]);
    }
}

// ---------------- LN2 ----------------
__global__ __launch_bounds__(256) void ln2_kernel(
        const float* __restrict__ y, const float* __restrict__ g,
        const float* __restrict__ b, unsigned short* __restrict__ h2) {
    int tid = threadIdx.x;
    int row = blockIdx.x * 4 + (tid >> 6);
    int lane = tid & 63;
    const float* xr = y + (size_t)row * DIMC;
    float v[12], s = 0.f;
    #pragma unroll
    for (int j = 0; j < 12; j++) { v[j] = xr[lane + 64 * j]; s += v[j]; }
    #pragma unroll
    for (int o = 32; o > 0; o >>= 1) s += __shfl_xor(s, o);
    float mean = s * (1.f / 768.f);
    float q = 0.f;
    #pragma unroll
    for (int j = 0; j < 12; j++) { float d = v[j] - mean; q += d * d; }
    #pragma unroll
    for (int o = 32; o > 0; o >>= 1) q += __shfl_xor(q, o);
    float inv = rsqrtf(q * (1.f / 768.f) + 1e-6f);
    unsigned short* out = h2 + (size_t)row * DIMC;
    #pragma unroll
    for (int j = 0; j < 12; j++) {
        int c = lane + 64 * j;
        out[c] = f2bf((v[j] - mean) * inv * g[c] + b[c]);
    }
}

// ---------------- build A_aug (q*0.125 | relh | relw | 0) and Vt ------------
// rel dots via MFMA (UNSCALED q): dots[i][r] = q[i] . RT[r].
// relh[i][c] = dots[i][13 + i/14 - c]; relw[i][c] = dots[i][27 + 13 + i%14 - c].
// q-columns scaled by 0.125 (pow2-exact on bf16) so attn's K is a pure copy.
__global__ __launch_bounds__(256) void build_aug(
        const unsigned short* __restrict__ qkvb,
        const float* __restrict__ relph, const float* __restrict__ relpw,
        unsigned short* __restrict__ Aaug, unsigned short* __restrict__ Vt) {
    __shared__ unsigned short qs[208 * 72];   // pitch 72: b128-aligned, 2-way banks
    __shared__ unsigned short rt[64 * 72];
    int tid = threadIdx.x;
    int bh = blockIdx.x, w = bh / HEADS, head = bh % HEADS;
    int lane = tid & 63, wave = tid >> 6;
    int l15 = lane & 15, q4 = lane >> 4, q8 = q4 * 8;
    size_t base = (size_t)w * NTOK * 2304 + head * 64;
    unsigned short* ab = Aaug + (size_t)bh * 256 * 96;

    // stage q -> qs (unscaled, for dots); write q*0.125 to ab cols 0..63
    for (int e = tid; e < 196 * 8; e += 256) {
        int t = e >> 3, s8 = (e & 7) * 8;
        bf16x8 qv = *(const bf16x8*)&qkvb[base + (size_t)t * 2304 + s8];
        *(bf16x8*)&qs[t * 72 + s8] = qv;
        bf16x8 qo;
        #pragma unroll
        for (int jj = 0; jj < 8; jj++)
            qo[jj] = (short)f2bf(bf2f((unsigned short)qv[jj]) * 0.125f);
        *(bf16x8*)&ab[t * 96 + s8] = qo;
    }
    for (int e = tid; e < 12 * 8; e += 256) {  // zero qs rows 196..207
        bf16x8 z = {};
        *(bf16x8*)&qs[(196 + (e >> 3)) * 72 + (e & 7) * 8] = z;
    }
    // stage RT tables (f32 -> bf16), rows 54..63 zero
    for (int e = tid; e < 64 * 8; e += 256) {
        int r = e >> 3, s8 = (e & 7) * 8;
        bf16x8 ov = {};
        if (r < 54) {
            const float* src = (r < 27 ? relph + (size_t)r * 64
                                       : relpw + (size_t)(r - 27) * 64) + s8;
            #pragma unroll
            for (int jj = 0; jj < 8; jj++) ov[jj] = (short)f2bf(src[jj]);
        }
        *(bf16x8*)&rt[r * 72 + s8] = ov;
    }
    // zero ab rows 196..255 (all 96 cols) and cols 92..95
    for (int e = tid; e < 60 * 12; e += 256) {
        bf16x8 z = {};
        *(bf16x8*)&ab[(size_t)(196 + e / 12) * 96 + (e % 12) * 8] = z;
    }
    for (int e = tid; e < 196; e += 256) {
        ab[e * 96 + 92] = 0; ab[e * 96 + 93] = 0;
        ab[e * 96 + 94] = 0; ab[e * 96 + 95] = 0;
    }
    __syncthreads();

    // rel MFMA + scatter into ab cols 64..91 (unscaled q)
    #pragma unroll
    for (int t = 0; t < 4; t++) {
        int it = wave * 4 + t;
        if (it >= 13) break;                      // wave-uniform
        bf16x8 a0 = *(bf16x8*)&qs[(it * 16 + l15) * 72 + q8];
        bf16x8 a1 = *(bf16x8*)&qs[(it * 16 + l15) * 72 + 32 + q8];
        #pragma unroll
        for (int rt4 = 0; rt4 < 4; rt4++) {
            bf16x8 b0 = *(bf16x8*)&rt[(rt4 * 16 + l15) * 72 + q8];
            bf16x8 b1 = *(bf16x8*)&rt[(rt4 * 16 + l15) * 72 + 32 + q8];
            f32x4 d4 = {};
            d4 = __builtin_amdgcn_mfma_f32_16x16x32_bf16(a0, b0, d4, 0, 0, 0);
            d4 = __builtin_amdgcn_mfma_f32_16x16x32_bf16(a1, b1, d4, 0, 0, 0);
            int rcol = rt4 * 16 + l15;
            #pragma unroll
            for (int r = 0; r < 4; r++) {
                int i = it * 16 + q4 * 4 + r;
                if (i < 196 && rcol < 54) {
                    if (rcol < 27) {
                        int c = 13 + i / 14 - rcol;
                        if (c >= 0 && c < 14) ab[i * 96 + 64 + c] = f2bf(d4[r]);
                    } else {
                        int c = 13 + i % 14 - (rcol - 27);
                        if (c >= 0 && c < 14) ab[i * 96 + 78 + c] = f2bf(d4[r]);
                    }
                }
            }
        }
    }

    // Vt[d][224]: vector read V, scalar global scatter (L2 write-combines)
    unsigned short* vtb = Vt + (size_t)bh * 64 * 224;
    for (int e = tid; e < 196 * 8; e += 256) {
        int j = e >> 3, dg = (e & 7) * 8;
        bf16x8 vv = *(const bf16x8*)&qkvb[base + 1536 + (size_t)j * 2304 + dg];
        #pragma unroll
        for (int k = 0; k < 8; k++)
            vtb[(size_t)(dg + k) * 224 + j] = (unsigned short)vv[k];
    }
    for (int e = tid; e < 64 * 28; e += 256)     // zero cols 196..223
        vtb[(size_t)(e / 28) * 224 + 196 + (e % 28)] = 0;
}

// ---------------- fused MFMA attention: one block per (window,head) --------
// s = (q*0.125)@k + relh + relw via one-hot K-columns. K rows gl2lds-copied
// (pre-swizzled segs); invalid rows (>=196) are garbage-but-masked.
__global__ __launch_bounds__(256) void attn_mfma(
        const unsigned short* __restrict__ qkvb,
        const unsigned short* __restrict__ Aaug,
        const unsigned short* __restrict__ Vt,
        unsigned short* __restrict__ out) {
    __shared__ unsigned short Kk[208 * 64];    // k rows, segs XOR'd by row&7
    __shared__ unsigned short Koh[208 * 40];   // one-hot cols, pitch 40
    __shared__ unsigned short Pls[4][64 * 44]; // per-wave P strip, pitch 44
    int tid = threadIdx.x;
    int bh = blockIdx.x, w = bh / HEADS, head = bh % HEADS;
    int wave = tid >> 6, lane = tid & 63;
    int l15 = lane & 15, q4 = lane >> 4, q8 = q4 * 8;
    size_t kbase = (size_t)w * NTOK * 2304 + head * 64 + 768;
    // stage K via global_load_lds: lane l -> row r0+(l>>3), LDS seg l&7,
    // global seg (l&7)^(l>>3) = (l&7)^(row&7)  [r0 is a multiple of 8]
    {
        int sw = ((lane & 7) ^ (lane >> 3)) * 8;
        for (int r0 = wave * 8; r0 < 208; r0 += 32) {
            int grow = r0 + (lane >> 3);
            if (grow > 195) grow = 195;          // rows >=196 masked in exp
            gl2lds16(&qkvb[kbase + (size_t)grow * 2304 + sw],
                     &Kk[r0 * 64 + lane * 8]);
        }
    }
    bf16x8 z8 = {};
    for (int e = tid; e < 208 * 5; e += 256)   // zero Koh
        *(bf16x8*)&Koh[(e / 5) * 40 + (e % 5) * 8] = z8;
    __syncthreads();                           // zeros before one-hots (same dwords)
    for (int e = tid; e < 196; e += 256) {
        Koh[e * 40 + e / WIN] = 0x3F80;        // bf16(1.0)
        Koh[e * 40 + 14 + e % WIN] = 0x3F80;
    }
    // A-frags from global (held in regs across all j-tiles)
    bf16x8 af[4][3];
    const unsigned short* abse = Aaug + (size_t)bh * 256 * 96;
    #pragma unroll
    for (int it = 0; it < 4; it++)
        #pragma unroll
        for (int c = 0; c < 3; c++)
            af[it][c] = *(const bf16x8*)&abse[(size_t)(wave * 64 + it * 16 + l15) * 96 + c * 32 + q8];
    __syncthreads();                           // K (vmcnt drained) + one-hots visible

    const unsigned short* vtb = Vt + (size_t)bh * 64 * 224;
    f32x4 o[4][4] = {};
    float lacc[4][4] = {{0.f}};
    bf16x8 bv[4];
    #pragma unroll
    for (int dt = 0; dt < 4; dt++)
        bv[dt] = *(const bf16x8*)&vtb[(dt * 16 + l15) * 224 + q8];

    for (int jp = 0; jp < 7; jp++) {
        f32x4 s[4][2] = {};
        #pragma unroll
        for (int half = 0; half < 2; half++) {
            int jt = jp * 2 + half;
            if (jt < 13) {
                int krow = jt * 16 + l15;
                #pragma unroll
                for (int c = 0; c < 2; c++) {
                    // deswizzle: global seg c*4+q4 lives at LDS seg ^(l15&7)
                    bf16x8 bk = *(bf16x8*)&Kk[krow * 64 + (((c * 4 + q4) ^ (l15 & 7)) * 8)];
                    #pragma unroll
                    for (int it = 0; it < 4; it++)
                        s[it][half] = __builtin_amdgcn_mfma_f32_16x16x32_bf16(
                            af[it][c], bk, s[it][half], 0, 0, 0);
                }
                bf16x8 bo = *(bf16x8*)&Koh[krow * 40 + q8];
                #pragma unroll
                for (int it = 0; it < 4; it++)
                    s[it][half] = __builtin_amdgcn_mfma_f32_16x16x32_bf16(
                        af[it][2], bo, s[it][half], 0, 0, 0);
            }
        }
        // exp phase — NO block barrier: Pls[wave] is wave-private, DS in-order
        #pragma unroll
        for (int half = 0; half < 2; half++) {
            int jt = jp * 2 + half;
            bool valid = (jt < 13) && (jt * 16 + l15) < 196;
            #pragma unroll
            for (int it = 0; it < 4; it++)
                #pragma unroll
                for (int r = 0; r < 4; r++) {
                    float p = valid ? __expf(s[it][half][r]) : 0.f;
                    unsigned short pb = f2bf(p);
                    lacc[it][r] += bf2f(pb);
                    Pls[wave][(it * 16 + q4 * 4 + r) * 44 + half * 16 + l15] = pb;
                }
        }
        asm volatile("s_waitcnt lgkmcnt(0)" ::: "memory");  // own P writes done
        bf16x8 ap[4];
        #pragma unroll
        for (int it = 0; it < 4; it++)
            ap[it] = *(bf16x8*)&Pls[wave][(it * 16 + l15) * 44 + q8];
        bf16x8 bvn[4];
        if (jp < 6) {
            #pragma unroll
            for (int dt = 0; dt < 4; dt++)
                bvn[dt] = *(const bf16x8*)&vtb[(dt * 16 + l15) * 224 + (jp + 1) * 32 + q8];
        }
        #pragma unroll
        for (int dt = 0; dt < 4; dt++)
            #pragma unroll
            for (int it = 0; it < 4; it++)
                o[it][dt] = __builtin_amdgcn_mfma_f32_16x16x32_bf16(
                    ap[it], bv[dt], o[it][dt], 0, 0, 0);
        if (jp < 6) {
            #pragma unroll
            for (int dt = 0; dt < 4; dt++) bv[dt] = bvn[dt];
        }
    }
    // row sums across the 16 j-lanes of each quad
    #pragma unroll
    for (int it = 0; it < 4; it++)
        #pragma unroll
        for (int r = 0; r < 4; r++) {
            float v = lacc[it][r];
            v += __shfl_xor(v, 1); v += __shfl_xor(v, 2);
            v += __shfl_xor(v, 4); v += __shfl_xor(v, 8);
            lacc[it][r] = 1.f / v;
        }
    // store O (win, token, head, d)
    #pragma unroll
    for (int it = 0; it < 4; it++) {
        int i0 = wave * 64 + it * 16 + q4 * 4;
        #pragma unroll
        for (int r = 0; r < 4; r++) {
            if (i0 + r < 196) {
                size_t rowb = (size_t)(w * NTOK + i0 + r) * DIMC + head * 64;
                #pragma unroll
                for (int dt = 0; dt < 4; dt++)
                    out[rowb + dt * 16 + l15] = f2bf(o[it][dt][r] * lacc[it][r]);
            }
        }
    }
}

// ---------------- MFMA GEMM (R10: 3-buffer 2-ahead counted vmcnt): ----------
// C = A(MxK bf16) @ Bt(NxK bf16)^T + bias.  BM=128, BN in {128,64}, BK=32.
// Counted vmcnt: barrier at iter t waits only for tile t's loads (vmcnt(LPT)
// leaves tile t+1 in flight); tile t+2 is issued into the buffer freed by
// iter t-1. EPI 0: bf16 store   EPI 1: fast exact-erf gelu -> bf16
// EPI 2: window-unpartition + x residual (f32)   EPI 3: + resid (f32)
template <int EPI, int BN>
__global__ __launch_bounds__(256) void mgemm(
        const unsigned short* __restrict__ A, const unsigned short* __restrict__ Bt,
        const float* __restrict__ bias, void* __restrict__ Cout,
        const float* __restrict__ resid, int M, int Nn, int K,
        int nbx, int nby) {
    const int NI = BN / 32;                 // per-wave n-frags
    constexpr int LPT = (BN == 128) ? 4 : 3;  // gl2lds16 per thread per tile
    __shared__ unsigned short As[3][128 * 32];
    __shared__ unsigned short Bs[3][BN * 32];
    int tid = threadIdx.x;
    int lane = tid & 63, wave = tid >> 6;
    int l15 = lane & 15, q4 = lane >> 4;
    int xq8 = (q4 ^ ((l15 >> 1) & 3)) * 8;  // swizzled frag segment (shorts)
    // ---- XCD swizzle ----
    int id = blockIdx.x;
    int per = nbx * 8;
    int s = id / per;
    int rem = id - s * per;
    int rmax = nby - s * 8; if (rmax > 8) rmax = 8;
    int bx = rem / rmax;
    int r_ = rem - bx * rmax;
    int by = s * 8 + r_;
    int m0 = by << 7, n0 = bx * BN;
    int wm = (wave >> 1) * 64, wn = (wave & 1) * (BN / 2);
    // staging: lane i -> row i/4, swizzled global seg; LDS dst = base + lane*16
    int srow0 = wave * 32 + (lane >> 2);
    int srow1 = srow0 + 16;
    int sseg = ((lane & 3) ^ ((lane >> 3) & 3)) * 8;   // shorts
    int rmA0 = m0 + srow0; if (rmA0 >= M) rmA0 = M - 1;   // clamp: rows>=M never stored
    int rmA1 = m0 + srow1; if (rmA1 >= M) rmA1 = M - 1;
    const unsigned short* gA0 = A + (size_t)rmA0 * K + sseg;
    const unsigned short* gA1 = A + (size_t)rmA1 * K + sseg;
    int browB = (BN == 128) ? srow0 : (wave * 16 + (lane >> 2));
    const unsigned short* gB0 = Bt + (size_t)(n0 + browB) * K + sseg;
    const unsigned short* gB1 = Bt + (size_t)(n0 + srow1) * K + sseg;  // BN=128 only
    int lofsA = wave * 1024 + lane * 8;
    int lofsB = ((BN == 128) ? wave * 1024 : wave * 512) + lane * 8;
    f32x4 acc[4][NI] = {};
    int nt = K >> 5;
    // prologue: stage tiles 0,1 into bufs 0,1 (issue order defines vmcnt FIFO)
    gl2lds16(gA0, &As[0][lofsA]);
    gl2lds16(gA1, &As[0][lofsA + 512]);
    gl2lds16(gB0, &Bs[0][lofsB]);
    if (BN == 128) gl2lds16(gB1, &Bs[0][lofsB + 512]);
    if (nt > 1) {
        gl2lds16(gA0 + 32, &As[1][lofsA]);
        gl2lds16(gA1 + 32, &As[1][lofsA + 512]);
        gl2lds16(gB0 + 32, &Bs[1][lofsB]);
        if (BN == 128) gl2lds16(gB1 + 32, &Bs[1][lofsB + 512]);
    }
    int cur = 0;
    for (int t = 0; t < nt; ++t) {
        if (t + 1 < nt) {
            // drain tile t only; tile t+1 (LPT loads) stays in flight
            asm volatile("s_waitcnt vmcnt(%0)" :: "i"(LPT) : "memory");
        } else {
            asm volatile("s_waitcnt vmcnt(0)" ::: "memory");
        }
        __builtin_amdgcn_s_barrier();
        if (t + 2 < nt) {                    // issue tile t+2 into freed buffer
            int b2 = cur + 2; if (b2 >= 3) b2 -= 3;
            int kn = (t + 2) << 5;
            gl2lds16(gA0 + kn, &As[b2][lofsA]);
            gl2lds16(gA1 + kn, &As[b2][lofsA + 512]);
            gl2lds16(gB0 + kn, &Bs[b2][lofsB]);
            if (BN == 128) gl2lds16(gB1 + kn, &Bs[b2][lofsB + 512]);
        }
        bf16x8 bfr[NI];
        #pragma unroll
        for (int ni = 0; ni < NI; ni++)
            bfr[ni] = *(bf16x8*)&Bs[cur][(wn + ni * 16 + l15) * 32 + xq8];
        #pragma unroll
        for (int mi = 0; mi < 4; mi++) {
            bf16x8 afr = *(bf16x8*)&As[cur][(wm + mi * 16 + l15) * 32 + xq8];
            #pragma unroll
            for (int ni = 0; ni < NI; ni++)
                acc[mi][ni] = __builtin_amdgcn_mfma_f32_16x16x32_bf16(
                    afr, bfr[ni], acc[mi][ni], 0, 0, 0);
        }
        cur = (cur == 2) ? 0 : cur + 1;
    }
    int q4r = (lane >> 4) * 4;
    #pragma unroll
    for (int mi = 0; mi < 4; mi++) {
        #pragma unroll
        for (int r = 0; r < 4; r++) {
            int row = m0 + wm + mi * 16 + q4r + r;
            if (row >= M) continue;
            if (EPI == 2) {
                int w = row / NTOK, t = row % NTOK;
                int bi = w / 25, wr = w % 25;
                int gy = (wr / 5) * WIN + t / WIN;
                int gx = (wr % 5) * WIN + t % WIN;
                if (gy >= 64 || gx >= 64) continue;
                size_t orow = ((size_t)((bi * 64 + gy) * 64 + gx)) * DIMC;
                #pragma unroll
                for (int ni = 0; ni < NI; ni++) {
                    int col = n0 + wn + ni * 16 + l15;
                    float v = acc[mi][ni][r] + bias[col];
                    ((float*)Cout)[orow + col] = resid[orow + col] + v;
                }
            } else {
                #pragma unroll
                for (int ni = 0; ni < NI; ni++) {
                    int col = n0 + wn + ni * 16 + l15;
                    float v = acc[mi][ni][r] + bias[col];
                    if (EPI == 0) {
                        ((unsigned short*)Cout)[(size_t)row * Nn + col] = f2bf(v);
                    } else if (EPI == 1) {
                        v = fast_gelu(v);
                        ((unsigned short*)Cout)[(size_t)row * Nn + col] = f2bf(v);
                    } else {
                        ((float*)Cout)[(size_t)row * Nn + col] =
                            resid[(size_t)row * Nn + col] + v;
                    }
                }
            }
        }
    }
}

// ---------------------------------------------------------------------------
extern "C" void kernel_launch(void* const* d_in, const int* in_sizes, int n_in,
                              void* d_out, int out_size, void* d_ws, size_t ws_size,
                              hipStream_t stream) {
    const float* x      = (const float*)d_in[0];
    const float* ln1_g  = (const float*)d_in[1];
    const float* ln1_b  = (const float*)d_in[2];
    const float* qkv_w  = (const float*)d_in[3];
    const float* qkv_b  = (const float*)d_in[4];
    const float* proj_w = (const float*)d_in[5];
    const float* proj_b = (const float*)d_in[6];
    const float* rel_h  = (const float*)d_in[7];
    const float* rel_w  = (const float*)d_in[8];
    const float* ln2_g  = (const float*)d_in[9];
    const float* ln2_b  = (const float*)d_in[10];
    const float* fc1_w  = (const float*)d_in[11];
    const float* fc1_b  = (const float*)d_in[12];
    const float* fc2_w  = (const float*)d_in[13];
    const float* fc2_b  = (const float*)d_in[14];
    float* out = (float*)d_out;
    char* ws = (char*)d_ws;

    // Workspace regions (max 121,061,376 B), liveness-checked (same as R3-R12):
    unsigned short* wt_qkv  = (unsigned short*)(ws);
    unsigned short* wt_proj = (unsigned short*)(ws + 3538944);
    unsigned short* wt_fc1  = (unsigned short*)(ws + 4718592);
    unsigned short* wt_fc2  = (unsigned short*)(ws + 9437184);
    unsigned short* qkvb    = (unsigned short*)(ws + 14155776);
    float*          yb      = (float*)        (ws + 14155776);
    unsigned short* h2      = (unsigned short*)(ws + 39321600);
    unsigned short* h1      = (unsigned short*)(ws + 59314176);
    unsigned short* attn_o  = h1;
    unsigned short* zb      = h1;
    unsigned short* Aaug    = (unsigned short*)(ws + 74366976);
    unsigned short* Vt      = (unsigned short*)(ws + 103858176);

    transpose_all<<<1728, 256, 0, stream>>>(
        qkv_w, wt_qkv, proj_w, wt_proj, fc1_w, wt_fc1, fc2_w, wt_fc2);

    ln1_win_kernel<<<(MROWS + 3) / 4, 256, 0, stream>>>(x, ln1_g, ln1_b, h1);

    mgemm<0, 128><<<18 * 77, 256, 0, stream>>>(
        h1, wt_qkv, qkv_b, qkvb, nullptr, MROWS, 2304, DIMC, 18, 77);

    build_aug<<<NWIN * HEADS, 256, 0, stream>>>(qkvb, rel_h, rel_w, Aaug, Vt);

    attn_mfma<<<NWIN * HEADS, 256, 0, stream>>>(qkvb, Aaug, Vt, attn_o);

    mgemm<2, 64><<<12 * 77, 256, 0, stream>>>(
        attn_o, wt_proj, proj_b, yb, x, MROWS, DIMC, DIMC, 12, 77);

    ln2_kernel<<<YROWS / 4, 256, 0, stream>>>(yb, ln2_g, ln2_b, h2);

    mgemm<1, 128><<<24 * 64, 256, 0, stream>>>(
        h2, wt_fc1, fc1_b, zb, nullptr, YROWS, MLP_HID, DIMC, 24, 64);

    mgemm<3, 64><<<12 * 64, 256, 0, stream>>>(
        zb, wt_fc2, fc2_b, out, yb, YROWS, DIMC, MLP_HID, 12, 64);
}

// Round 9
// 406.752 us; speedup vs baseline: 1.3361x; 1.0209x over previous
//
#include <hip/hip_runtime.h>
#include <hip/hip_bf16.h>
#include <math.h>

// ---------------------------------------------------------------------------
// Swin/SAM-style block. R17: build_aug fused INTO attn (one kernel per
// (win,head)). Eliminates the Aaug(29.5MB)+Vt(17.2MB) global round-trips, a
// launch, and duplicate q/K staging (~90MB). K fragments read DIRECT from
// qkvb (L2-resident; each element used once per wave, so LDS staging bought
// nothing) -- dropping the Kk region keeps LDS at 81,152B -> 2 blocks/CU.
// Phase A {qs,rt staged; rel-dots MFMA -> swizzled relc; V-transpose -> Vt;
// one-hots -> Koh overlaying dead qs} then the R16 j-loop. Valid outputs
// bitwise-identical to R16 (invalid rows clamp+mask instead of zero-fill).
// GEMMs/LNs/transpose unchanged from R16 (best measured, 415.3us).
// ---------------------------------------------------------------------------

#define DIMC 768
#define HEADS 12
#define WIN 14
#define NTOK 196
#define NWIN 50
#define MROWS 9800
#define YROWS 8192
#define MLP_HID 3072

using bf16x8 = __attribute__((ext_vector_type(8))) short;
using f32x4  = __attribute__((ext_vector_type(4))) float;

__device__ __forceinline__ float bf2f(unsigned short u) {
    return __uint_as_float(((unsigned)u) << 16);
}
__device__ __forceinline__ unsigned short f2bf(float f) {
    unsigned u = __float_as_uint(f);
    unsigned r = (u + 0x7fffu + ((u >> 16) & 1u)) >> 16;   // round-nearest-even
    return (unsigned short)r;
}
__device__ __forceinline__ void gl2lds16(const unsigned short* g, unsigned short* l) {
    __builtin_amdgcn_global_load_lds(
        (const __attribute__((address_space(1))) void*)g,
        (__attribute__((address_space(3))) void*)l, 16, 0, 0);
}

// Branchless exact-enough gelu: 0.5*v*(1+erf(v/sqrt(2))).
// erf via Abramowitz-Stegun 7.1.26 (max err 1.5e-7 < bf16 quantum).
__device__ __forceinline__ float fast_gelu(float v) {
    float u = v * 0.70710678118654752f;
    float a = fabsf(u);
    float t = __builtin_amdgcn_rcpf(fmaf(0.3275911f, a, 1.0f));
    float p = t * fmaf(t, fmaf(t, fmaf(t, fmaf(t, 1.061405429f, -1.453152027f),
                       1.421413741f), -0.284496736f), 0.254829592f);
    float e = __expf(-u * u);
    float er = fmaf(-p, e, 1.0f);            // erf(|u|)
    er = copysignf(er, v);
    return 0.5f * v * (1.0f + er);
}

// ---------------- fused 4-way weight transpose: W (K x N, f32) -> Wt (N x K, bf16)
// block ranges: [0,432) qkv  [432,576) proj  [576,1152) fc1  [1152,1728) fc2
__global__ __launch_bounds__(256) void transpose_all(
        const float* __restrict__ Wq, unsigned short* __restrict__ Tq,
        const float* __restrict__ Wp, unsigned short* __restrict__ Tp,
        const float* __restrict__ W1, unsigned short* __restrict__ T1,
        const float* __restrict__ W2, unsigned short* __restrict__ T2) {
    int id = blockIdx.x;
    const float* W; unsigned short* Wt; int K, N, nbx, rel;
    if (id < 432)       { W = Wq; Wt = Tq; K = 768;  N = 2304; nbx = 36; rel = id; }
    else if (id < 576)  { W = Wp; Wt = Tp; K = 768;  N = 768;  nbx = 12; rel = id - 432; }
    else if (id < 1152) { W = W1; Wt = T1; K = 768;  N = 3072; nbx = 48; rel = id - 576; }
    else                { W = W2; Wt = T2; K = 3072; N = 768;  nbx = 12; rel = id - 1152; }
    int bx = rel % nbx, by = rel / nbx;
    __shared__ float t[64][65];
    int k0 = by << 6, n0 = bx << 6;
    int tn = threadIdx.x & 63;
    int tk = threadIdx.x >> 6;
    #pragma unroll
    for (int r = 0; r < 16; r++) {
        int k = tk + r * 4;
        t[k][tn] = W[(size_t)(k0 + k) * N + n0 + tn];
    }
    __syncthreads();
    #pragma unroll
    for (int r = 0; r < 16; r++) {
        int n = tk + r * 4;
        Wt[(size_t)(n0 + n) * K + k0 + tn] = f2bf(t[tn][n]);
    }
}

// ---------------- LN1 + window partition (zeros in padding) ----------------
__global__ __launch_bounds__(256) void ln1_win_kernel(
        const float* __restrict__ x, const float* __restrict__ g,
        const float* __restrict__ b, unsigned short* __restrict__ h1) {
    int tid = threadIdx.x;
    int row = blockIdx.x * 4 + (tid >> 6);
    int lane = tid & 63;
    if (row >= MROWS) return;
    int w = row / NTOK, t = row % NTOK;
    int bi = w / 25, wr = w % 25;
    int gy = (wr / 5) * WIN + t / WIN;
    int gx = (wr % 5) * WIN + t % WIN;
    unsigned short* out = h1 + (size_t)row * DIMC;
    if (gy >= 64 || gx >= 64) {           // reference pads AFTER LN -> zeros
        #pragma unroll
        for (int j = 0; j < 12; j++) out[lane + 64 * j] = 0;
        return;
    }
    const float* xr = x + ((size_t)((bi * 64 + gy) * 64 + gx)) * DIMC;
    float v[12], s = 0.f;
    #pragma unroll
    for (int j = 0; j < 12; j++) { v[j] = xr[lane + 64 * j]; s += v[j]; }
    #pragma unroll
    for (int o = 32; o > 0; o >>= 1) s += __shfl_xor(s, o);
    float mean = s * (1.f / 768.f);
    float q = 0.f;
    #pragma unroll
    for (int j = 0; j < 12; j++) { float d = v[j] - mean; q += d * d; }
    #pragma unroll
    for (int o = 32; o > 0; o >>= 1) q += __shfl_xor(q, o);
    float inv = rsqrtf(q * (1.f / 768.f) + 1e-6f);
    #pragma unroll
    for (int j = 0; j < 12; j++) {
        int c = lane + 64 * j;
        out[c] = f2bf((v[j] - mean) * inv * g[c] + b[c]);
    }
}

// ---------------- LN2 ----------------
__global__ __launch_bounds__(256) void ln2_kernel(
        const float* __restrict__ y, const float* __restrict__ g,
        const float* __restrict__ b, unsigned short* __restrict__ h2) {
    int tid = threadIdx.x;
    int row = blockIdx.x * 4 + (tid >> 6);
    int lane = tid & 63;
    const float* xr = y + (size_t)row * DIMC;
    float v[12], s = 0.f;
    #pragma unroll
    for (int j = 0; j < 12; j++) { v[j] = xr[lane + 64 * j]; s += v[j]; }
    #pragma unroll
    for (int o = 32; o > 0; o >>= 1) s += __shfl_xor(s, o);
    float mean = s * (1.f / 768.f);
    float q = 0.f;
    #pragma unroll
    for (int j = 0; j < 12; j++) { float d = v[j] - mean; q += d * d; }
    #pragma unroll
    for (int o = 32; o > 0; o >>= 1) q += __shfl_xor(q, o);
    float inv = rsqrtf(q * (1.f / 768.f) + 1e-6f);
    unsigned short* out = h2 + (size_t)row * DIMC;
    #pragma unroll
    for (int j = 0; j < 12; j++) {
        int c = lane + 64 * j;
        out[c] = f2bf((v[j] - mean) * inv * g[c] + b[c]);
    }
}

// ---------------- fused rel-dots + V-transpose + attention -----------------
// One block per (window,head). LDS map (bytes):
//   phase A: qs[208*72] @0 (29952), rt[64*72] @29952 (9216)
//   phase B: Koh[196*40] @0 (15680), Pls[4][64*44] @15680 (22528)
//   persistent: Vt[64*224] @39168 (28672), relc[208*32, seg-XOR] @67840 (13312)
// Total 81152 -> 2 blocks/CU. K frags read direct from qkvb (L2).
// s = (q*0.125)@k + relh + relw (one-hot Koh x relc-table MFMA add).
__global__ __launch_bounds__(256) void attn_fused(
        const unsigned short* __restrict__ qkvb,
        const float* __restrict__ relph, const float* __restrict__ relpw,
        unsigned short* __restrict__ out) {
    __shared__ __align__(16) char smem[81152];
    unsigned short* qs   = (unsigned short*)smem;             // [208*72]
    unsigned short* rt   = (unsigned short*)(smem + 29952);   // [64*72]
    unsigned short* Koh  = (unsigned short*)smem;             // [196*40]
    unsigned short* Pls  = (unsigned short*)(smem + 15680);   // [4][64*44]
    unsigned short* Vt   = (unsigned short*)(smem + 39168);   // [64*224]
    unsigned short* relc = (unsigned short*)(smem + 67840);   // [208*32] swizzled
    int tid = threadIdx.x;
    int bh = blockIdx.x, w = bh / HEADS, head = bh % HEADS;
    int wave = tid >> 6, lane = tid & 63;
    int l15 = lane & 15, q4 = lane >> 4, q8 = q4 * 8;
    size_t qb = (size_t)w * NTOK * 2304 + head * 64;
    size_t kb = qb + 768, vb = qb + 1536;

    // ---- phase A: stage qs, rt; zero relc; build Vt ----
    for (int e = tid; e < 196 * 8; e += 256) {
        int t = e >> 3, s8 = (e & 7) * 8;
        *(bf16x8*)&qs[t * 72 + s8] = *(const bf16x8*)&qkvb[qb + (size_t)t * 2304 + s8];
    }
    {
        bf16x8 z = {};
        for (int e = tid; e < 12 * 8; e += 256)
            *(bf16x8*)&qs[(196 + (e >> 3)) * 72 + (e & 7) * 8] = z;
        for (int e = tid; e < 208 * 4; e += 256)
            *(bf16x8*)&relc[(e >> 2) * 32 + (e & 3) * 8] = z;
    }
    for (int e = tid; e < 64 * 8; e += 256) {
        int r = e >> 3, s8 = (e & 7) * 8;
        bf16x8 ov = {};
        if (r < 54) {
            const float* src = (r < 27 ? relph + (size_t)r * 64
                                       : relpw + (size_t)(r - 27) * 64) + s8;
            #pragma unroll
            for (int jj = 0; jj < 8; jj++) ov[jj] = (short)f2bf(src[jj]);
        }
        *(bf16x8*)&rt[r * 72 + s8] = ov;
    }
    for (int e = tid; e < 196 * 8; e += 256) {   // V transpose scatter
        int j = e >> 3, dg = (e & 7) * 8;
        bf16x8 vv = *(const bf16x8*)&qkvb[vb + (size_t)j * 2304 + dg];
        #pragma unroll
        for (int k = 0; k < 8; k++)
            Vt[(dg + k) * 224 + j] = (unsigned short)vv[k];
    }
    for (int e = tid; e < 64 * 28; e += 256)     // zero Vt cols 196..223
        Vt[(e / 28) * 224 + 196 + (e % 28)] = 0;
    __syncthreads();                             // B1: qs/rt/relc-zero/Vt done

    // af[it][0..1] = q*0.125 (pow2-exact); rows >=196 clamped (masked later)
    bf16x8 af[4][3];
    #pragma unroll
    for (int it = 0; it < 4; it++) {
        int arow = wave * 64 + it * 16 + l15;
        if (arow > 195) arow = 195;
        #pragma unroll
        for (int c = 0; c < 2; c++) {
            bf16x8 t8 = *(bf16x8*)&qs[arow * 72 + c * 32 + q8];
            #pragma unroll
            for (int jj = 0; jj < 8; jj++)
                af[it][c][jj] = (short)f2bf(bf2f((unsigned short)t8[jj]) * 0.125f);
        }
    }
    // rel dots MFMA (unscaled q) -> scatter into swizzled relc
    #pragma unroll
    for (int t = 0; t < 4; t++) {
        int it = wave * 4 + t;
        if (it >= 13) break;                      // wave-uniform
        bf16x8 a0 = *(bf16x8*)&qs[(it * 16 + l15) * 72 + q8];
        bf16x8 a1 = *(bf16x8*)&qs[(it * 16 + l15) * 72 + 32 + q8];
        #pragma unroll
        for (int rt4 = 0; rt4 < 4; rt4++) {
            bf16x8 b0 = *(bf16x8*)&rt[(rt4 * 16 + l15) * 72 + q8];
            bf16x8 b1 = *(bf16x8*)&rt[(rt4 * 16 + l15) * 72 + 32 + q8];
            f32x4 d4 = {};
            d4 = __builtin_amdgcn_mfma_f32_16x16x32_bf16(a0, b0, d4, 0, 0, 0);
            d4 = __builtin_amdgcn_mfma_f32_16x16x32_bf16(a1, b1, d4, 0, 0, 0);
            int rcol = rt4 * 16 + l15;
            #pragma unroll
            for (int r = 0; r < 4; r++) {
                int i = it * 16 + q4 * 4 + r;
                if (i < 196 && rcol < 54) {
                    int cc = -1;
                    if (rcol < 27) {
                        int c = 13 + i / 14 - rcol;
                        if (c >= 0 && c < 14) cc = c;
                    } else {
                        int c = 13 + i % 14 - (rcol - 27);
                        if (c >= 0 && c < 14) cc = 14 + c;
                    }
                    if (cc >= 0)
                        relc[i * 32 + (((cc >> 3) ^ (i & 3)) << 3) + (cc & 7)] =
                            f2bf(d4[r]);
                }
            }
        }
    }
    __syncthreads();                             // B2: qs/rt dead, relc complete
    {
        bf16x8 z = {};
        for (int e = tid; e < 196 * 5; e += 256) // zero Koh (over dead qs)
            *(bf16x8*)&Koh[(e / 5) * 40 + (e % 5) * 8] = z;
    }
    __syncthreads();                             // B3: zeros before one-hots
    for (int e = tid; e < 196; e += 256) {
        Koh[e * 40 + e / WIN] = 0x3F80;          // bf16(1.0)
        Koh[e * 40 + 14 + e % WIN] = 0x3F80;
    }
    // af[it][2] from swizzled relc (rows clamped)
    #pragma unroll
    for (int it = 0; it < 4; it++) {
        int arow = wave * 64 + it * 16 + l15;
        if (arow > 195) arow = 195;
        af[it][2] = *(bf16x8*)&relc[arow * 32 + ((q4 ^ (arow & 3)) << 3)];
    }
    __syncthreads();                             // B4: Koh ready; Pls region free

    f32x4 o[4][4] = {};
    float lacc[4][4] = {{0.f}};
    bf16x8 bv[4];
    #pragma unroll
    for (int dt = 0; dt < 4; dt++)
        bv[dt] = *(bf16x8*)&Vt[(dt * 16 + l15) * 224 + q8];

    for (int jp = 0; jp < 7; jp++) {
        f32x4 s[4][2] = {};
        #pragma unroll
        for (int half = 0; half < 2; half++) {
            int jt = jp * 2 + half;
            if (jt < 13) {
                int krow = jt * 16 + l15;
                if (krow > 195) krow = 195;      // garbage masked in exp
                const unsigned short* kr = qkvb + kb + (size_t)krow * 2304;
                bf16x8 bk0 = *(const bf16x8*)&kr[q8];        // direct from L2
                bf16x8 bk1 = *(const bf16x8*)&kr[32 + q8];
                bf16x8 bo  = *(bf16x8*)&Koh[krow * 40 + q8];
                #pragma unroll
                for (int it = 0; it < 4; it++) {
                    s[it][half] = __builtin_amdgcn_mfma_f32_16x16x32_bf16(
                        af[it][0], bk0, s[it][half], 0, 0, 0);
                    s[it][half] = __builtin_amdgcn_mfma_f32_16x16x32_bf16(
                        af[it][1], bk1, s[it][half], 0, 0, 0);
                    s[it][half] = __builtin_amdgcn_mfma_f32_16x16x32_bf16(
                        af[it][2], bo, s[it][half], 0, 0, 0);
                }
            }
        }
        // exp phase — no block barrier: Pls[wave] is wave-private, DS in-order
        unsigned short* pw = Pls + wave * (64 * 44);
        #pragma unroll
        for (int half = 0; half < 2; half++) {
            int jt = jp * 2 + half;
            bool valid = (jt < 13) && (jt * 16 + l15) < 196;
            #pragma unroll
            for (int it = 0; it < 4; it++)
                #pragma unroll
                for (int r = 0; r < 4; r++) {
                    float p = valid ? __expf(s[it][half][r]) : 0.f;
                    unsigned short pb = f2bf(p);
                    lacc[it][r] += bf2f(pb);
                    pw[(it * 16 + q4 * 4 + r) * 44 + half * 16 + l15] = pb;
                }
        }
        asm volatile("s_waitcnt lgkmcnt(0)" ::: "memory");  // own P writes done
        bf16x8 ap[4];
        #pragma unroll
        for (int it = 0; it < 4; it++)
            ap[it] = *(bf16x8*)&pw[(it * 16 + l15) * 44 + q8];
        bf16x8 bvn[4];
        if (jp < 6) {
            #pragma unroll
            for (int dt = 0; dt < 4; dt++)
                bvn[dt] = *(bf16x8*)&Vt[(dt * 16 + l15) * 224 + (jp + 1) * 32 + q8];
        }
        #pragma unroll
        for (int dt = 0; dt < 4; dt++)
            #pragma unroll
            for (int it = 0; it < 4; it++)
                o[it][dt] = __builtin_amdgcn_mfma_f32_16x16x32_bf16(
                    ap[it], bv[dt], o[it][dt], 0, 0, 0);
        if (jp < 6) {
            #pragma unroll
            for (int dt = 0; dt < 4; dt++) bv[dt] = bvn[dt];
        }
    }
    // row sums across the 16 j-lanes of each quad
    #pragma unroll
    for (int it = 0; it < 4; it++)
        #pragma unroll
        for (int r = 0; r < 4; r++) {
            float v = lacc[it][r];
            v += __shfl_xor(v, 1); v += __shfl_xor(v, 2);
            v += __shfl_xor(v, 4); v += __shfl_xor(v, 8);
            lacc[it][r] = 1.f / v;
        }
    // store O (win, token, head, d)
    #pragma unroll
    for (int it = 0; it < 4; it++) {
        int i0 = wave * 64 + it * 16 + q4 * 4;
        #pragma unroll
        for (int r = 0; r < 4; r++) {
            if (i0 + r < 196) {
                size_t rowb = (size_t)(w * NTOK + i0 + r) * DIMC + head * 64;
                #pragma unroll
                for (int dt = 0; dt < 4; dt++)
                    out[rowb + dt * 16 + l15] = f2bf(o[it][dt][r] * lacc[it][r]);
            }
        }
    }
}

// ---------------- MFMA GEMM (R10: 3-buffer 2-ahead counted vmcnt): ----------
// C = A(MxK bf16) @ Bt(NxK bf16)^T + bias.  BM=128, BN in {128,64}, BK=32.
// Counted vmcnt: barrier at iter t waits only for tile t's loads (vmcnt(LPT)
// leaves tile t+1 in flight); tile t+2 is issued into the buffer freed by
// iter t-1. EPI 0: bf16 store   EPI 1: fast exact-erf gelu -> bf16
// EPI 2: window-unpartition + x residual (f32)   EPI 3: + resid (f32)
template <int EPI, int BN>
__global__ __launch_bounds__(256) void mgemm(
        const unsigned short* __restrict__ A, const unsigned short* __restrict__ Bt,
        const float* __restrict__ bias, void* __restrict__ Cout,
        const float* __restrict__ resid, int M, int Nn, int K,
        int nbx, int nby) {
    const int NI = BN / 32;                 // per-wave n-frags
    constexpr int LPT = (BN == 128) ? 4 : 3;  // gl2lds16 per thread per tile
    __shared__ unsigned short As[3][128 * 32];
    __shared__ unsigned short Bs[3][BN * 32];
    int tid = threadIdx.x;
    int lane = tid & 63, wave = tid >> 6;
    int l15 = lane & 15, q4 = lane >> 4;
    int xq8 = (q4 ^ ((l15 >> 1) & 3)) * 8;  // swizzled frag segment (shorts)
    // ---- XCD swizzle ----
    int id = blockIdx.x;
    int per = nbx * 8;
    int s = id / per;
    int rem = id - s * per;
    int rmax = nby - s * 8; if (rmax > 8) rmax = 8;
    int bx = rem / rmax;
    int r_ = rem - bx * rmax;
    int by = s * 8 + r_;
    int m0 = by << 7, n0 = bx * BN;
    int wm = (wave >> 1) * 64, wn = (wave & 1) * (BN / 2);
    // staging: lane i -> row i/4, swizzled global seg; LDS dst = base + lane*16
    int srow0 = wave * 32 + (lane >> 2);
    int srow1 = srow0 + 16;
    int sseg = ((lane & 3) ^ ((lane >> 3) & 3)) * 8;   // shorts
    int rmA0 = m0 + srow0; if (rmA0 >= M) rmA0 = M - 1;   // clamp: rows>=M never stored
    int rmA1 = m0 + srow1; if (rmA1 >= M) rmA1 = M - 1;
    const unsigned short* gA0 = A + (size_t)rmA0 * K + sseg;
    const unsigned short* gA1 = A + (size_t)rmA1 * K + sseg;
    int browB = (BN == 128) ? srow0 : (wave * 16 + (lane >> 2));
    const unsigned short* gB0 = Bt + (size_t)(n0 + browB) * K + sseg;
    const unsigned short* gB1 = Bt + (size_t)(n0 + srow1) * K + sseg;  // BN=128 only
    int lofsA = wave * 1024 + lane * 8;
    int lofsB = ((BN == 128) ? wave * 1024 : wave * 512) + lane * 8;
    f32x4 acc[4][NI] = {};
    int nt = K >> 5;
    // prologue: stage tiles 0,1 into bufs 0,1 (issue order defines vmcnt FIFO)
    gl2lds16(gA0, &As[0][lofsA]);
    gl2lds16(gA1, &As[0][lofsA + 512]);
    gl2lds16(gB0, &Bs[0][lofsB]);
    if (BN == 128) gl2lds16(gB1, &Bs[0][lofsB + 512]);
    if (nt > 1) {
        gl2lds16(gA0 + 32, &As[1][lofsA]);
        gl2lds16(gA1 + 32, &As[1][lofsA + 512]);
        gl2lds16(gB0 + 32, &Bs[1][lofsB]);
        if (BN == 128) gl2lds16(gB1 + 32, &Bs[1][lofsB + 512]);
    }
    int cur = 0;
    for (int t = 0; t < nt; ++t) {
        if (t + 1 < nt) {
            // drain tile t only; tile t+1 (LPT loads) stays in flight
            asm volatile("s_waitcnt vmcnt(%0)" :: "i"(LPT) : "memory");
        } else {
            asm volatile("s_waitcnt vmcnt(0)" ::: "memory");
        }
        __builtin_amdgcn_s_barrier();
        if (t + 2 < nt) {                    // issue tile t+2 into freed buffer
            int b2 = cur + 2; if (b2 >= 3) b2 -= 3;
            int kn = (t + 2) << 5;
            gl2lds16(gA0 + kn, &As[b2][lofsA]);
            gl2lds16(gA1 + kn, &As[b2][lofsA + 512]);
            gl2lds16(gB0 + kn, &Bs[b2][lofsB]);
            if (BN == 128) gl2lds16(gB1 + kn, &Bs[b2][lofsB + 512]);
        }
        bf16x8 bfr[NI];
        #pragma unroll
        for (int ni = 0; ni < NI; ni++)
            bfr[ni] = *(bf16x8*)&Bs[cur][(wn + ni * 16 + l15) * 32 + xq8];
        #pragma unroll
        for (int mi = 0; mi < 4; mi++) {
            bf16x8 afr = *(bf16x8*)&As[cur][(wm + mi * 16 + l15) * 32 + xq8];
            #pragma unroll
            for (int ni = 0; ni < NI; ni++)
                acc[mi][ni] = __builtin_amdgcn_mfma_f32_16x16x32_bf16(
                    afr, bfr[ni], acc[mi][ni], 0, 0, 0);
        }
        cur = (cur == 2) ? 0 : cur + 1;
    }
    int q4r = (lane >> 4) * 4;
    #pragma unroll
    for (int mi = 0; mi < 4; mi++) {
        #pragma unroll
        for (int r = 0; r < 4; r++) {
            int row = m0 + wm + mi * 16 + q4r + r;
            if (row >= M) continue;
            if (EPI == 2) {
                int w = row / NTOK, t = row % NTOK;
                int bi = w / 25, wr = w % 25;
                int gy = (wr / 5) * WIN + t / WIN;
                int gx = (wr % 5) * WIN + t % WIN;
                if (gy >= 64 || gx >= 64) continue;
                size_t orow = ((size_t)((bi * 64 + gy) * 64 + gx)) * DIMC;
                #pragma unroll
                for (int ni = 0; ni < NI; ni++) {
                    int col = n0 + wn + ni * 16 + l15;
                    float v = acc[mi][ni][r] + bias[col];
                    ((float*)Cout)[orow + col] = resid[orow + col] + v;
                }
            } else {
                #pragma unroll
                for (int ni = 0; ni < NI; ni++) {
                    int col = n0 + wn + ni * 16 + l15;
                    float v = acc[mi][ni][r] + bias[col];
                    if (EPI == 0) {
                        ((unsigned short*)Cout)[(size_t)row * Nn + col] = f2bf(v);
                    } else if (EPI == 1) {
                        v = fast_gelu(v);
                        ((unsigned short*)Cout)[(size_t)row * Nn + col] = f2bf(v);
                    } else {
                        ((float*)Cout)[(size_t)row * Nn + col] =
                            resid[(size_t)row * Nn + col] + v;
                    }
                }
            }
        }
    }
}

// ---------------------------------------------------------------------------
extern "C" void kernel_launch(void* const* d_in, const int* in_sizes, int n_in,
                              void* d_out, int out_size, void* d_ws, size_t ws_size,
                              hipStream_t stream) {
    const float* x      = (const float*)d_in[0];
    const float* ln1_g  = (const float*)d_in[1];
    const float* ln1_b  = (const float*)d_in[2];
    const float* qkv_w  = (const float*)d_in[3];
    const float* qkv_b  = (const float*)d_in[4];
    const float* proj_w = (const float*)d_in[5];
    const float* proj_b = (const float*)d_in[6];
    const float* rel_h  = (const float*)d_in[7];
    const float* rel_w  = (const float*)d_in[8];
    const float* ln2_g  = (const float*)d_in[9];
    const float* ln2_b  = (const float*)d_in[10];
    const float* fc1_w  = (const float*)d_in[11];
    const float* fc1_b  = (const float*)d_in[12];
    const float* fc2_w  = (const float*)d_in[13];
    const float* fc2_b  = (const float*)d_in[14];
    float* out = (float*)d_out;
    char* ws = (char*)d_ws;

    // Workspace regions (max 121,061,376 B), liveness-checked (Aaug/Vt
    // regions from R16 no longer used -- fused into attn LDS):
    unsigned short* wt_qkv  = (unsigned short*)(ws);
    unsigned short* wt_proj = (unsigned short*)(ws + 3538944);
    unsigned short* wt_fc1  = (unsigned short*)(ws + 4718592);
    unsigned short* wt_fc2  = (unsigned short*)(ws + 9437184);
    unsigned short* qkvb    = (unsigned short*)(ws + 14155776);
    float*          yb      = (float*)        (ws + 14155776);
    unsigned short* h2      = (unsigned short*)(ws + 39321600);
    unsigned short* h1      = (unsigned short*)(ws + 59314176);
    unsigned short* attn_o  = h1;
    unsigned short* zb      = h1;

    transpose_all<<<1728, 256, 0, stream>>>(
        qkv_w, wt_qkv, proj_w, wt_proj, fc1_w, wt_fc1, fc2_w, wt_fc2);

    ln1_win_kernel<<<(MROWS + 3) / 4, 256, 0, stream>>>(x, ln1_g, ln1_b, h1);

    mgemm<0, 128><<<18 * 77, 256, 0, stream>>>(
        h1, wt_qkv, qkv_b, qkvb, nullptr, MROWS, 2304, DIMC, 18, 77);

    attn_fused<<<NWIN * HEADS, 256, 0, stream>>>(qkvb, rel_h, rel_w, attn_o);

    mgemm<2, 64><<<12 * 77, 256, 0, stream>>>(
        attn_o, wt_proj, proj_b, yb, x, MROWS, DIMC, DIMC, 12, 77);

    ln2_kernel<<<YROWS / 4, 256, 0, stream>>>(yb, ln2_g, ln2_b, h2);

    mgemm<1, 128><<<24 * 64, 256, 0, stream>>>(
        h2, wt_fc1, fc1_b, zb, nullptr, YROWS, MLP_HID, DIMC, 24, 64);

    mgemm<3, 64><<<12 * 64, 256, 0, stream>>>(
        zb, wt_fc2, fc2_b, out, yb, YROWS, DIMC, MLP_HID, 12, 64);
}